// Round 2
// baseline (777.628 us; speedup 1.0000x reference)
//
#include <hip/hip_runtime.h>
#include <hip/hip_bf16.h>

// GNN: 2-layer GCN (N=50000, E=800000, F=128, H=256) + mean-pool (G=512) + MLP head (257->32->4)
// Key identity: segment_sum((xW)[src]*norm) == (segment_sum(x[src]*norm)) @ W  (GCN agg is linear)
// So each layer = aggregate first (cheaper dims for L1), then GEMM with fused bias+ReLU.
//   prep:  deg histogram -> dinv -> exclusive scan -> CSR scatter (by dst, w = dinv[s]*dinv[d])
//   L1: agg128(x) -> a0 ; h1 = relu(a0 @ W1 + b1)
//   L2: agg256(h1) -> a1 ; h2 = relu(a1 @ W2 + b2)
//   head: per-graph block: binary-search node range in sorted batch, mean-pool, 257->32->4 MLP

#define NN 50000
#define EE 800000
#define FDIM 128
#define HDIM 256
#define GG 512

// ---------------- prep kernels ----------------

__global__ void hist_kernel(const int* __restrict__ dst, int* __restrict__ deg, int e) {
    int i = blockIdx.x * blockDim.x + threadIdx.x;
    int stride = gridDim.x * blockDim.x;
    for (; i < e; i += stride) atomicAdd(&deg[dst[i]], 1);
}

__global__ void dinv_kernel(const int* __restrict__ deg, float* __restrict__ dinv, int n) {
    int i = blockIdx.x * blockDim.x + threadIdx.x;
    if (i < n) dinv[i] = rsqrtf((float)deg[i] + 1.0f);  // +1 self loop; always > 0
}

// single-block exclusive scan of deg -> row_off[0..n], also zeroes fill[]
__global__ void scan_kernel(const int* __restrict__ deg, int* __restrict__ row_off,
                            int* __restrict__ fill, int n) {
    __shared__ int s[256];
    __shared__ int carry;
    int tid = threadIdx.x;
    if (tid == 0) carry = 0;
    __syncthreads();
    for (int base = 0; base < n; base += 256) {
        int i = base + tid;
        int v = (i < n) ? deg[i] : 0;
        s[tid] = v;
        __syncthreads();
        #pragma unroll
        for (int off = 1; off < 256; off <<= 1) {
            int t = (tid >= off) ? s[tid - off] : 0;
            __syncthreads();
            s[tid] += t;
            __syncthreads();
        }
        int incl = s[tid];
        int excl = incl - v;
        if (i < n) { row_off[i] = carry + excl; fill[i] = 0; }
        __syncthreads();
        if (tid == 255) carry += s[255];
        __syncthreads();
    }
    if (tid == 0) row_off[n] = carry;
}

__global__ void scatter_kernel(const int* __restrict__ src, const int* __restrict__ dst,
                               const int* __restrict__ row_off, int* __restrict__ fill,
                               const float* __restrict__ dinv,
                               int* __restrict__ csr_src, float* __restrict__ csr_w, int e) {
    int i = blockIdx.x * blockDim.x + threadIdx.x;
    int stride = gridDim.x * blockDim.x;
    for (; i < e; i += stride) {
        int s = src[i], d = dst[i];
        int pos = row_off[d] + atomicAdd(&fill[d], 1);
        csr_src[pos] = s;
        csr_w[pos] = dinv[s] * dinv[d];
    }
}

// ---------------- GCN aggregation (pure): out[d] = sum_e in[src_e]*w_e + in[d]*dinv[d]^2 ----------------
// one wave per node; D=128 -> float2/lane, D=256 -> float4/lane

__global__ __launch_bounds__(256) void gcn_agg128(const float* __restrict__ in,
                                                  const int* __restrict__ row_off,
                                                  const int* __restrict__ csr_src,
                                                  const float* __restrict__ csr_w,
                                                  const float* __restrict__ dinv,
                                                  float* __restrict__ out, int n) {
    int wave = threadIdx.x >> 6;
    int lane = threadIdx.x & 63;
    int node = blockIdx.x * 4 + wave;
    if (node >= n) return;
    float di = dinv[node];
    float w0 = di * di;
    float2 hv = *(const float2*)&in[(size_t)node * 128 + lane * 2];
    float2 acc = {hv.x * w0, hv.y * w0};
    int beg = row_off[node], end = row_off[node + 1];
    for (int e = beg; e < end; ++e) {
        int s = csr_src[e];
        float w = csr_w[e];
        float2 v = *(const float2*)&in[(size_t)s * 128 + lane * 2];
        acc.x = fmaf(v.x, w, acc.x);
        acc.y = fmaf(v.y, w, acc.y);
    }
    *(float2*)&out[(size_t)node * 128 + lane * 2] = acc;
}

__global__ __launch_bounds__(256) void gcn_agg256(const float* __restrict__ in,
                                                  const int* __restrict__ row_off,
                                                  const int* __restrict__ csr_src,
                                                  const float* __restrict__ csr_w,
                                                  const float* __restrict__ dinv,
                                                  float* __restrict__ out, int n) {
    int wave = threadIdx.x >> 6;
    int lane = threadIdx.x & 63;
    int node = blockIdx.x * 4 + wave;
    if (node >= n) return;
    float di = dinv[node];
    float w0 = di * di;
    float4 hv = *(const float4*)&in[(size_t)node * 256 + lane * 4];
    float4 acc = {hv.x * w0, hv.y * w0, hv.z * w0, hv.w * w0};
    int beg = row_off[node], end = row_off[node + 1];
    for (int e = beg; e < end; ++e) {
        int s = csr_src[e];
        float w = csr_w[e];
        float4 v = *(const float4*)&in[(size_t)s * 256 + lane * 4];
        acc.x = fmaf(v.x, w, acc.x);
        acc.y = fmaf(v.y, w, acc.y);
        acc.z = fmaf(v.z, w, acc.z);
        acc.w = fmaf(v.w, w, acc.w);
    }
    *(float4*)&out[(size_t)node * 256 + lane * 4] = acc;
}

// ---------------- fp32 tiled GEMM + bias + ReLU: C = relu(A[M,K] @ B[K,Nc] + bias) ----------------
// BM=BN=64, BK=16, 256 threads, 4x4 per thread. K multiple of 16, Nc multiple of 64.

__global__ __launch_bounds__(256) void gemm_bias_relu(const float* __restrict__ A,
                                                      const float* __restrict__ B,
                                                      const float* __restrict__ bias,
                                                      float* __restrict__ C,
                                                      int M, int K, int Nc) {
    __shared__ float As[16][65];   // [k][m], +1 pad
    __shared__ float Bs[16][64];   // [k][n]
    int tid = threadIdx.x;
    int bm = blockIdx.x * 64;
    int bn = blockIdx.y * 64;
    int tx = tid & 15, ty = tid >> 4;

    int a_m = tid >> 2;            // 0..63
    int a_k = (tid & 3) * 4;       // 0,4,8,12
    int b_k = tid >> 4;            // 0..15
    int b_n = (tid & 15) * 4;      // 0..60

    float acc[4][4] = {};
    for (int k0 = 0; k0 < K; k0 += 16) {
        float4 av = {0.f, 0.f, 0.f, 0.f};
        int gm = bm + a_m;
        if (gm < M) av = *(const float4*)&A[(size_t)gm * K + k0 + a_k];
        As[a_k + 0][a_m] = av.x;
        As[a_k + 1][a_m] = av.y;
        As[a_k + 2][a_m] = av.z;
        As[a_k + 3][a_m] = av.w;
        *(float4*)&Bs[b_k][b_n] = *(const float4*)&B[(size_t)(k0 + b_k) * Nc + bn + b_n];
        __syncthreads();
        #pragma unroll
        for (int kk = 0; kk < 16; ++kk) {
            float a[4], b[4];
            #pragma unroll
            for (int i = 0; i < 4; ++i) a[i] = As[kk][ty * 4 + i];
            #pragma unroll
            for (int j = 0; j < 4; ++j) b[j] = Bs[kk][tx * 4 + j];
            #pragma unroll
            for (int i = 0; i < 4; ++i)
                #pragma unroll
                for (int j = 0; j < 4; ++j)
                    acc[i][j] = fmaf(a[i], b[j], acc[i][j]);
        }
        __syncthreads();
    }
    float4 bv = *(const float4*)&bias[bn + tx * 4];
    #pragma unroll
    for (int i = 0; i < 4; ++i) {
        int m = bm + ty * 4 + i;
        if (m < M) {
            float4 cv;
            cv.x = fmaxf(acc[i][0] + bv.x, 0.f);
            cv.y = fmaxf(acc[i][1] + bv.y, 0.f);
            cv.z = fmaxf(acc[i][2] + bv.z, 0.f);
            cv.w = fmaxf(acc[i][3] + bv.w, 0.f);
            *(float4*)&C[(size_t)m * Nc + bn + tx * 4] = cv;
        }
    }
}

// ---------------- pool + head: one block per graph ----------------

__device__ __forceinline__ int lower_bound_i(const int* __restrict__ a, int n, int v) {
    int lo = 0, hi = n;
    while (lo < hi) {
        int mid = (lo + hi) >> 1;
        if (a[mid] < v) lo = mid + 1; else hi = mid;
    }
    return lo;
}

__global__ __launch_bounds__(256) void pool_head(const float* __restrict__ h,
                                                 const int* __restrict__ batch,
                                                 const float* __restrict__ num_atoms,
                                                 const float* __restrict__ W3, const float* __restrict__ b3,
                                                 const float* __restrict__ W4, const float* __restrict__ b4,
                                                 float* __restrict__ out, int n) {
    int g = blockIdx.x;
    int tid = threadIdx.x;
    __shared__ int s_lo, s_hi;
    if (tid == 0) {
        s_lo = lower_bound_i(batch, n, g);
        s_hi = lower_bound_i(batch, n, g + 1);
    }
    __syncthreads();
    int lo = s_lo, hi = s_hi;
    float sum = 0.f;
    for (int i = lo; i < hi; ++i) sum += h[(size_t)i * HDIM + tid];
    float cnt = (float)(hi - lo);
    float pooled = sum / fmaxf(cnt, 1.0f);

    __shared__ float zin[HDIM + 1];
    __shared__ float z[32];
    zin[tid] = pooled;
    if (tid == 0) zin[HDIM] = num_atoms[g];
    __syncthreads();
    if (tid < 32) {
        float a = b3[tid];
        for (int k = 0; k < HDIM + 1; ++k) a = fmaf(zin[k], W3[k * 32 + tid], a);
        z[tid] = fmaxf(a, 0.f);
    }
    __syncthreads();
    if (tid < 4) {
        float a = b4[tid];
        #pragma unroll
        for (int k = 0; k < 32; ++k) a = fmaf(z[k], W4[k * 4 + tid], a);
        out[g * 4 + tid] = a;
    }
}

// ---------------- launch ----------------

extern "C" void kernel_launch(void* const* d_in, const int* in_sizes, int n_in,
                              void* d_out, int out_size, void* d_ws, size_t ws_size,
                              hipStream_t stream) {
    const float* x         = (const float*)d_in[0];
    const int*   edge_idx  = (const int*)d_in[1];
    const int*   batch     = (const int*)d_in[2];
    const float* num_atoms = (const float*)d_in[3];
    const float* W1 = (const float*)d_in[4];
    const float* b1 = (const float*)d_in[5];
    const float* W2 = (const float*)d_in[6];
    const float* b2 = (const float*)d_in[7];
    const float* W3 = (const float*)d_in[8];
    const float* b3 = (const float*)d_in[9];
    const float* W4 = (const float*)d_in[10];
    const float* b4 = (const float*)d_in[11];
    float* out = (float*)d_out;

    const int n = NN, e = EE;
    const int* e_src = edge_idx;
    const int* e_dst = edge_idx + e;

    // workspace carve-out (256B aligned).  Total ~110 MB:
    //   small arrays ~0.8MB, csr 6.4MB, bufT 51.2MB, bufH 51.2MB
    //   a0 (agg-of-x, [N,128]) aliases the low half of bufT (dead before bufT's first write).
    char* ws = (char*)d_ws;
    size_t off = 0;
    auto carve = [&](size_t bytes) -> void* {
        void* p = ws + off;
        off = (off + bytes + 255) & ~(size_t)255;
        return p;
    };
    int*   deg_i   = (int*)carve((size_t)n * 4);
    int*   row_off = (int*)carve((size_t)(n + 1) * 4);
    int*   fill    = (int*)carve((size_t)n * 4);
    float* dinv    = (float*)carve((size_t)n * 4);
    int*   csr_src = (int*)carve((size_t)e * 4);
    float* csr_w   = (float*)carve((size_t)e * 4);
    float* bufT    = (float*)carve((size_t)n * HDIM * 4);  // agg outputs (a0 aliased low half, a1 full)
    float* bufH    = (float*)carve((size_t)n * HDIM * 4);  // h1 then h2
    float* a0 = bufT;  // [N,128] alias — dead before agg256 writes bufT
    (void)ws_size; (void)n_in; (void)in_sizes; (void)out_size;

    hipMemsetAsync(deg_i, 0, (size_t)n * 4, stream);
    hist_kernel<<<1024, 256, 0, stream>>>(e_dst, deg_i, e);
    dinv_kernel<<<(n + 255) / 256, 256, 0, stream>>>(deg_i, dinv, n);
    scan_kernel<<<1, 256, 0, stream>>>(deg_i, row_off, fill, n);
    scatter_kernel<<<1024, 256, 0, stream>>>(e_src, e_dst, row_off, fill, dinv, csr_src, csr_w, e);

    dim3 gemm_grid((n + 63) / 64, HDIM / 64);
    // layer 1: a0 = agg(x) [N,128]; h1 = relu(a0 @ W1 + b1) [N,256]
    gcn_agg128<<<(n + 3) / 4, 256, 0, stream>>>(x, row_off, csr_src, csr_w, dinv, a0, n);
    gemm_bias_relu<<<gemm_grid, 256, 0, stream>>>(a0, W1, b1, bufH, n, FDIM, HDIM);
    // layer 2: a1 = agg(h1) [N,256]; h2 = relu(a1 @ W2 + b2) [N,256]
    gcn_agg256<<<(n + 3) / 4, 256, 0, stream>>>(bufH, row_off, csr_src, csr_w, dinv, bufT, n);
    gemm_bias_relu<<<gemm_grid, 256, 0, stream>>>(bufT, W2, b2, bufH, n, HDIM, HDIM);
    // pool + head
    pool_head<<<GG, 256, 0, stream>>>(bufH, batch, num_atoms, W3, b3, W4, b4, out, n);
}

// Round 3
// 582.286 us; speedup vs baseline: 1.3355x; 1.3355x over previous
//
#include <hip/hip_runtime.h>
#include <hip/hip_bf16.h>

// GNN: 2-layer GCN (N=50000, E=800000, F=128, H=256) + mean-pool (G=512) + MLP head (257->32->4)
// Key identity: segment_sum((xW)[src]*norm) == (segment_sum(x[src]*norm)) @ W  (GCN agg is linear)
//   prep:  deg histogram -> hierarchical exclusive scan (3 tiny kernels, dinv fused) -> CSR scatter
//   L1: agg128(x) -> a0 ; h1 = relu(a0 @ W1 + b1)
//   L2: agg256(h1) -> a1 ; h2 = relu(a1 @ W2 + b2)
//   head: per-graph block: binary-search node range in sorted batch, mean-pool, 257->32->4 MLP
// R2 fix: single-block scan was 216us (top dispatch, 28% of runtime) -> 3-phase scan ~12us.

#define NN 50000
#define EE 800000
#define FDIM 128
#define HDIM 256
#define GG 512
#define SCAN_NB ((NN + 255) / 256)   // 196 blocks, fits one 256-wide scan

// ---------------- prep kernels ----------------

__global__ void hist_kernel(const int* __restrict__ dst, int* __restrict__ deg, int e) {
    int i = blockIdx.x * blockDim.x + threadIdx.x;
    int stride = gridDim.x * blockDim.x;
    for (; i < e; i += stride) atomicAdd(&deg[dst[i]], 1);
}

// phase 1: per-block exclusive scan of deg -> row_off (block-local), block total -> blk_sums;
// also computes dinv = rsqrt(deg+1) (self-loop) since deg is already in hand.
__global__ __launch_bounds__(256) void scan_part(const int* __restrict__ deg,
                                                 int* __restrict__ row_off,
                                                 int* __restrict__ blk_sums,
                                                 float* __restrict__ dinv, int n) {
    __shared__ int s[256];
    int tid = threadIdx.x;
    int i = blockIdx.x * 256 + tid;
    int v = (i < n) ? deg[i] : 0;
    if (i < n) dinv[i] = rsqrtf((float)v + 1.0f);
    s[tid] = v;
    __syncthreads();
    #pragma unroll
    for (int off = 1; off < 256; off <<= 1) {
        int t = (tid >= off) ? s[tid - off] : 0;
        __syncthreads();
        s[tid] += t;
        __syncthreads();
    }
    if (i < n) row_off[i] = s[tid] - v;             // block-local exclusive
    if (tid == 255) blk_sums[blockIdx.x] = s[255];  // block total
}

// phase 2: single 256-wide block scans blk_sums (SCAN_NB<=256) exclusive in place
__global__ __launch_bounds__(256) void scan_sums(int* __restrict__ blk_sums, int nb) {
    __shared__ int s[256];
    int tid = threadIdx.x;
    int v = (tid < nb) ? blk_sums[tid] : 0;
    s[tid] = v;
    __syncthreads();
    #pragma unroll
    for (int off = 1; off < 256; off <<= 1) {
        int t = (tid >= off) ? s[tid - off] : 0;
        __syncthreads();
        s[tid] += t;
        __syncthreads();
    }
    if (tid < nb) blk_sums[tid] = s[tid] - v;
}

// phase 3: add block offsets, zero fill[], set row_off[n] = e (hist of e edges sums to e)
__global__ __launch_bounds__(256) void scan_add(int* __restrict__ row_off,
                                                const int* __restrict__ blk_sums,
                                                int* __restrict__ fill, int n, int e) {
    int i = blockIdx.x * 256 + threadIdx.x;
    if (i < n) {
        row_off[i] += blk_sums[blockIdx.x];
        fill[i] = 0;
    }
    if (i == 0) row_off[n] = e;
}

__global__ void scatter_kernel(const int* __restrict__ src, const int* __restrict__ dst,
                               const int* __restrict__ row_off, int* __restrict__ fill,
                               const float* __restrict__ dinv,
                               int* __restrict__ csr_src, float* __restrict__ csr_w, int e) {
    int i = blockIdx.x * blockDim.x + threadIdx.x;
    int stride = gridDim.x * blockDim.x;
    for (; i < e; i += stride) {
        int s = src[i], d = dst[i];
        int pos = row_off[d] + atomicAdd(&fill[d], 1);
        csr_src[pos] = s;
        csr_w[pos] = dinv[s] * dinv[d];
    }
}

// ---------------- GCN aggregation (pure): out[d] = sum_e in[src_e]*w_e + in[d]*dinv[d]^2 ----------------
// one wave per node; D=128 -> float2/lane, D=256 -> float4/lane

__global__ __launch_bounds__(256) void gcn_agg128(const float* __restrict__ in,
                                                  const int* __restrict__ row_off,
                                                  const int* __restrict__ csr_src,
                                                  const float* __restrict__ csr_w,
                                                  const float* __restrict__ dinv,
                                                  float* __restrict__ out, int n) {
    int wave = threadIdx.x >> 6;
    int lane = threadIdx.x & 63;
    int node = blockIdx.x * 4 + wave;
    if (node >= n) return;
    float di = dinv[node];
    float w0 = di * di;
    float2 hv = *(const float2*)&in[(size_t)node * 128 + lane * 2];
    float2 acc = {hv.x * w0, hv.y * w0};
    int beg = row_off[node], end = row_off[node + 1];
    for (int e = beg; e < end; ++e) {
        int s = csr_src[e];
        float w = csr_w[e];
        float2 v = *(const float2*)&in[(size_t)s * 128 + lane * 2];
        acc.x = fmaf(v.x, w, acc.x);
        acc.y = fmaf(v.y, w, acc.y);
    }
    *(float2*)&out[(size_t)node * 128 + lane * 2] = acc;
}

__global__ __launch_bounds__(256) void gcn_agg256(const float* __restrict__ in,
                                                  const int* __restrict__ row_off,
                                                  const int* __restrict__ csr_src,
                                                  const float* __restrict__ csr_w,
                                                  const float* __restrict__ dinv,
                                                  float* __restrict__ out, int n) {
    int wave = threadIdx.x >> 6;
    int lane = threadIdx.x & 63;
    int node = blockIdx.x * 4 + wave;
    if (node >= n) return;
    float di = dinv[node];
    float w0 = di * di;
    float4 hv = *(const float4*)&in[(size_t)node * 256 + lane * 4];
    float4 acc = {hv.x * w0, hv.y * w0, hv.z * w0, hv.w * w0};
    int beg = row_off[node], end = row_off[node + 1];
    for (int e = beg; e < end; ++e) {
        int s = csr_src[e];
        float w = csr_w[e];
        float4 v = *(const float4*)&in[(size_t)s * 256 + lane * 4];
        acc.x = fmaf(v.x, w, acc.x);
        acc.y = fmaf(v.y, w, acc.y);
        acc.z = fmaf(v.z, w, acc.z);
        acc.w = fmaf(v.w, w, acc.w);
    }
    *(float4*)&out[(size_t)node * 256 + lane * 4] = acc;
}

// ---------------- fp32 tiled GEMM + bias + ReLU: C = relu(A[M,K] @ B[K,Nc] + bias) ----------------
// BM=BN=64, BK=16, 256 threads, 4x4 per thread. K multiple of 16, Nc multiple of 64.

__global__ __launch_bounds__(256) void gemm_bias_relu(const float* __restrict__ A,
                                                      const float* __restrict__ B,
                                                      const float* __restrict__ bias,
                                                      float* __restrict__ C,
                                                      int M, int K, int Nc) {
    __shared__ float As[16][65];   // [k][m], +1 pad
    __shared__ float Bs[16][64];   // [k][n]
    int tid = threadIdx.x;
    int bm = blockIdx.x * 64;
    int bn = blockIdx.y * 64;
    int tx = tid & 15, ty = tid >> 4;

    int a_m = tid >> 2;            // 0..63
    int a_k = (tid & 3) * 4;       // 0,4,8,12
    int b_k = tid >> 4;            // 0..15
    int b_n = (tid & 15) * 4;      // 0..60

    float acc[4][4] = {};
    for (int k0 = 0; k0 < K; k0 += 16) {
        float4 av = {0.f, 0.f, 0.f, 0.f};
        int gm = bm + a_m;
        if (gm < M) av = *(const float4*)&A[(size_t)gm * K + k0 + a_k];
        As[a_k + 0][a_m] = av.x;
        As[a_k + 1][a_m] = av.y;
        As[a_k + 2][a_m] = av.z;
        As[a_k + 3][a_m] = av.w;
        *(float4*)&Bs[b_k][b_n] = *(const float4*)&B[(size_t)(k0 + b_k) * Nc + bn + b_n];
        __syncthreads();
        #pragma unroll
        for (int kk = 0; kk < 16; ++kk) {
            float a[4], b[4];
            #pragma unroll
            for (int i = 0; i < 4; ++i) a[i] = As[kk][ty * 4 + i];
            #pragma unroll
            for (int j = 0; j < 4; ++j) b[j] = Bs[kk][tx * 4 + j];
            #pragma unroll
            for (int i = 0; i < 4; ++i)
                #pragma unroll
                for (int j = 0; j < 4; ++j)
                    acc[i][j] = fmaf(a[i], b[j], acc[i][j]);
        }
        __syncthreads();
    }
    float4 bv = *(const float4*)&bias[bn + tx * 4];
    #pragma unroll
    for (int i = 0; i < 4; ++i) {
        int m = bm + ty * 4 + i;
        if (m < M) {
            float4 cv;
            cv.x = fmaxf(acc[i][0] + bv.x, 0.f);
            cv.y = fmaxf(acc[i][1] + bv.y, 0.f);
            cv.z = fmaxf(acc[i][2] + bv.z, 0.f);
            cv.w = fmaxf(acc[i][3] + bv.w, 0.f);
            *(float4*)&C[(size_t)m * Nc + bn + tx * 4] = cv;
        }
    }
}

// ---------------- pool + head: one block per graph ----------------

__device__ __forceinline__ int lower_bound_i(const int* __restrict__ a, int n, int v) {
    int lo = 0, hi = n;
    while (lo < hi) {
        int mid = (lo + hi) >> 1;
        if (a[mid] < v) lo = mid + 1; else hi = mid;
    }
    return lo;
}

__global__ __launch_bounds__(256) void pool_head(const float* __restrict__ h,
                                                 const int* __restrict__ batch,
                                                 const float* __restrict__ num_atoms,
                                                 const float* __restrict__ W3, const float* __restrict__ b3,
                                                 const float* __restrict__ W4, const float* __restrict__ b4,
                                                 float* __restrict__ out, int n) {
    int g = blockIdx.x;
    int tid = threadIdx.x;
    __shared__ int s_lo, s_hi;
    if (tid == 0) {
        s_lo = lower_bound_i(batch, n, g);
        s_hi = lower_bound_i(batch, n, g + 1);
    }
    __syncthreads();
    int lo = s_lo, hi = s_hi;
    float sum = 0.f;
    for (int i = lo; i < hi; ++i) sum += h[(size_t)i * HDIM + tid];
    float cnt = (float)(hi - lo);
    float pooled = sum / fmaxf(cnt, 1.0f);

    __shared__ float zin[HDIM + 1];
    __shared__ float z[32];
    zin[tid] = pooled;
    if (tid == 0) zin[HDIM] = num_atoms[g];
    __syncthreads();
    if (tid < 32) {
        float a = b3[tid];
        for (int k = 0; k < HDIM + 1; ++k) a = fmaf(zin[k], W3[k * 32 + tid], a);
        z[tid] = fmaxf(a, 0.f);
    }
    __syncthreads();
    if (tid < 4) {
        float a = b4[tid];
        #pragma unroll
        for (int k = 0; k < 32; ++k) a = fmaf(z[k], W4[k * 4 + tid], a);
        out[g * 4 + tid] = a;
    }
}

// ---------------- launch ----------------

extern "C" void kernel_launch(void* const* d_in, const int* in_sizes, int n_in,
                              void* d_out, int out_size, void* d_ws, size_t ws_size,
                              hipStream_t stream) {
    const float* x         = (const float*)d_in[0];
    const int*   edge_idx  = (const int*)d_in[1];
    const int*   batch     = (const int*)d_in[2];
    const float* num_atoms = (const float*)d_in[3];
    const float* W1 = (const float*)d_in[4];
    const float* b1 = (const float*)d_in[5];
    const float* W2 = (const float*)d_in[6];
    const float* b2 = (const float*)d_in[7];
    const float* W3 = (const float*)d_in[8];
    const float* b3 = (const float*)d_in[9];
    const float* W4 = (const float*)d_in[10];
    const float* b4 = (const float*)d_in[11];
    float* out = (float*)d_out;

    const int n = NN, e = EE;
    const int* e_src = edge_idx;
    const int* e_dst = edge_idx + e;

    // workspace carve-out (256B aligned). Total ~110 MB.
    char* ws = (char*)d_ws;
    size_t off = 0;
    auto carve = [&](size_t bytes) -> void* {
        void* p = ws + off;
        off = (off + bytes + 255) & ~(size_t)255;
        return p;
    };
    int*   deg_i    = (int*)carve((size_t)n * 4);
    int*   row_off  = (int*)carve((size_t)(n + 1) * 4);
    int*   fill     = (int*)carve((size_t)n * 4);
    int*   blk_sums = (int*)carve((size_t)256 * 4);
    float* dinv     = (float*)carve((size_t)n * 4);
    int*   csr_src  = (int*)carve((size_t)e * 4);
    float* csr_w    = (float*)carve((size_t)e * 4);
    float* bufT     = (float*)carve((size_t)n * HDIM * 4);  // agg outputs (a0 aliased low half, a1 full)
    float* bufH     = (float*)carve((size_t)n * HDIM * 4);  // h1 then h2
    float* a0 = bufT;  // [N,128] alias — dead before agg256 writes bufT
    (void)ws_size; (void)n_in; (void)in_sizes; (void)out_size;

    hipMemsetAsync(deg_i, 0, (size_t)n * 4, stream);
    hist_kernel<<<1024, 256, 0, stream>>>(e_dst, deg_i, e);
    scan_part<<<SCAN_NB, 256, 0, stream>>>(deg_i, row_off, blk_sums, dinv, n);
    scan_sums<<<1, 256, 0, stream>>>(blk_sums, SCAN_NB);
    scan_add<<<SCAN_NB, 256, 0, stream>>>(row_off, blk_sums, fill, n, e);
    scatter_kernel<<<1024, 256, 0, stream>>>(e_src, e_dst, row_off, fill, dinv, csr_src, csr_w, e);

    dim3 gemm_grid((n + 63) / 64, HDIM / 64);
    // layer 1: a0 = agg(x) [N,128]; h1 = relu(a0 @ W1 + b1) [N,256]
    gcn_agg128<<<(n + 3) / 4, 256, 0, stream>>>(x, row_off, csr_src, csr_w, dinv, a0, n);
    gemm_bias_relu<<<gemm_grid, 256, 0, stream>>>(a0, W1, b1, bufH, n, FDIM, HDIM);
    // layer 2: a1 = agg(h1) [N,256]; h2 = relu(a1 @ W2 + b2) [N,256]
    gcn_agg256<<<(n + 3) / 4, 256, 0, stream>>>(bufH, row_off, csr_src, csr_w, dinv, bufT, n);
    gemm_bias_relu<<<gemm_grid, 256, 0, stream>>>(bufT, W2, b2, bufH, n, HDIM, HDIM);
    // pool + head
    pool_head<<<GG, 256, 0, stream>>>(bufH, batch, num_atoms, W3, b3, W4, b4, out, n);
}

// Round 4
// 545.714 us; speedup vs baseline: 1.4250x; 1.0670x over previous
//
#include <hip/hip_runtime.h>
#include <hip/hip_bf16.h>

// GNN: 2-layer GCN (N=50000, E=800000, F=128, H=256) + mean-pool (G=512) + MLP head (257->32->4)
// Key identity: segment_sum((xW)[src]*norm) == (segment_sum(x[src]*norm)) @ W  (GCN agg is linear)
//   prep:  deg histogram -> hierarchical scan (dinv fused) -> packed CSR scatter (int2{src,w})
//   L1: agg128(x) -> a0 ; h1 = relu(a0 @ W1 + b1)
//   L2: agg256(h1) -> a1 ; h2 = relu(a1 @ W2 + b2)
//   head: per-graph block: binary-search node range in sorted batch, mean-pool, 257->32->4 MLP
// R3: scan fixed (216us -> ~10us). R4: 128x128/8x8 fp32 GEMM; packed CSR + unroll-2 agg loop.

#define NN 50000
#define EE 800000
#define FDIM 128
#define HDIM 256
#define GG 512
#define SCAN_NB ((NN + 255) / 256)   // 196 blocks, fits one 256-wide scan

// ---------------- prep kernels ----------------

__global__ void hist_kernel(const int* __restrict__ dst, int* __restrict__ deg, int e) {
    int i = blockIdx.x * blockDim.x + threadIdx.x;
    int stride = gridDim.x * blockDim.x;
    for (; i < e; i += stride) atomicAdd(&deg[dst[i]], 1);
}

// phase 1: per-block exclusive scan of deg -> row_off (block-local), block total -> blk_sums;
// also dinv = rsqrt(deg+1) (self-loop).
__global__ __launch_bounds__(256) void scan_part(const int* __restrict__ deg,
                                                 int* __restrict__ row_off,
                                                 int* __restrict__ blk_sums,
                                                 float* __restrict__ dinv, int n) {
    __shared__ int s[256];
    int tid = threadIdx.x;
    int i = blockIdx.x * 256 + tid;
    int v = (i < n) ? deg[i] : 0;
    if (i < n) dinv[i] = rsqrtf((float)v + 1.0f);
    s[tid] = v;
    __syncthreads();
    #pragma unroll
    for (int off = 1; off < 256; off <<= 1) {
        int t = (tid >= off) ? s[tid - off] : 0;
        __syncthreads();
        s[tid] += t;
        __syncthreads();
    }
    if (i < n) row_off[i] = s[tid] - v;
    if (tid == 255) blk_sums[blockIdx.x] = s[255];
}

// phase 2: one block scans blk_sums (SCAN_NB<=256) exclusive in place
__global__ __launch_bounds__(256) void scan_sums(int* __restrict__ blk_sums, int nb) {
    __shared__ int s[256];
    int tid = threadIdx.x;
    int v = (tid < nb) ? blk_sums[tid] : 0;
    s[tid] = v;
    __syncthreads();
    #pragma unroll
    for (int off = 1; off < 256; off <<= 1) {
        int t = (tid >= off) ? s[tid - off] : 0;
        __syncthreads();
        s[tid] += t;
        __syncthreads();
    }
    if (tid < nb) blk_sums[tid] = s[tid] - v;
}

// phase 3: add block offsets, zero fill[], row_off[n] = e
__global__ __launch_bounds__(256) void scan_add(int* __restrict__ row_off,
                                                const int* __restrict__ blk_sums,
                                                int* __restrict__ fill, int n, int e) {
    int i = blockIdx.x * 256 + threadIdx.x;
    if (i < n) {
        row_off[i] += blk_sums[blockIdx.x];
        fill[i] = 0;
    }
    if (i == 0) row_off[n] = e;
}

// packed CSR entry: .x = src node, .y = float bits of edge weight
__global__ void scatter_kernel(const int* __restrict__ src, const int* __restrict__ dst,
                               const int* __restrict__ row_off, int* __restrict__ fill,
                               const float* __restrict__ dinv,
                               int2* __restrict__ csr, int e) {
    int i = blockIdx.x * blockDim.x + threadIdx.x;
    int stride = gridDim.x * blockDim.x;
    for (; i < e; i += stride) {
        int s = src[i], d = dst[i];
        int pos = row_off[d] + atomicAdd(&fill[d], 1);
        csr[pos] = make_int2(s, __float_as_int(dinv[s] * dinv[d]));
    }
}

// ---------------- GCN aggregation (pure): out[d] = sum_e in[src_e]*w_e + in[d]*dinv[d]^2 ----------------
// one wave per node, unroll-2 edge loop for memory-level parallelism

__global__ __launch_bounds__(256) void gcn_agg128(const float* __restrict__ in,
                                                  const int* __restrict__ row_off,
                                                  const int2* __restrict__ csr,
                                                  const float* __restrict__ dinv,
                                                  float* __restrict__ out, int n) {
    int wave = threadIdx.x >> 6;
    int lane = threadIdx.x & 63;
    int node = blockIdx.x * 4 + wave;
    if (node >= n) return;
    float di = dinv[node];
    float w0 = di * di;
    float2 hv = *(const float2*)&in[(size_t)node * 128 + lane * 2];
    float2 acc = {hv.x * w0, hv.y * w0};
    int beg = row_off[node], end = row_off[node + 1];
    int e = beg;
    for (; e + 2 <= end; e += 2) {
        int2 p0 = csr[e], p1 = csr[e + 1];
        float2 v0 = *(const float2*)&in[(size_t)p0.x * 128 + lane * 2];
        float2 v1 = *(const float2*)&in[(size_t)p1.x * 128 + lane * 2];
        float wa = __int_as_float(p0.y), wb = __int_as_float(p1.y);
        acc.x = fmaf(v0.x, wa, acc.x);
        acc.y = fmaf(v0.y, wa, acc.y);
        acc.x = fmaf(v1.x, wb, acc.x);
        acc.y = fmaf(v1.y, wb, acc.y);
    }
    if (e < end) {
        int2 p = csr[e];
        float2 v = *(const float2*)&in[(size_t)p.x * 128 + lane * 2];
        float w = __int_as_float(p.y);
        acc.x = fmaf(v.x, w, acc.x);
        acc.y = fmaf(v.y, w, acc.y);
    }
    *(float2*)&out[(size_t)node * 128 + lane * 2] = acc;
}

__global__ __launch_bounds__(256) void gcn_agg256(const float* __restrict__ in,
                                                  const int* __restrict__ row_off,
                                                  const int2* __restrict__ csr,
                                                  const float* __restrict__ dinv,
                                                  float* __restrict__ out, int n) {
    int wave = threadIdx.x >> 6;
    int lane = threadIdx.x & 63;
    int node = blockIdx.x * 4 + wave;
    if (node >= n) return;
    float di = dinv[node];
    float w0 = di * di;
    float4 hv = *(const float4*)&in[(size_t)node * 256 + lane * 4];
    float4 acc = {hv.x * w0, hv.y * w0, hv.z * w0, hv.w * w0};
    int beg = row_off[node], end = row_off[node + 1];
    int e = beg;
    for (; e + 2 <= end; e += 2) {
        int2 p0 = csr[e], p1 = csr[e + 1];
        float4 v0 = *(const float4*)&in[(size_t)p0.x * 256 + lane * 4];
        float4 v1 = *(const float4*)&in[(size_t)p1.x * 256 + lane * 4];
        float wa = __int_as_float(p0.y), wb = __int_as_float(p1.y);
        acc.x = fmaf(v0.x, wa, acc.x);
        acc.y = fmaf(v0.y, wa, acc.y);
        acc.z = fmaf(v0.z, wa, acc.z);
        acc.w = fmaf(v0.w, wa, acc.w);
        acc.x = fmaf(v1.x, wb, acc.x);
        acc.y = fmaf(v1.y, wb, acc.y);
        acc.z = fmaf(v1.z, wb, acc.z);
        acc.w = fmaf(v1.w, wb, acc.w);
    }
    if (e < end) {
        int2 p = csr[e];
        float4 v = *(const float4*)&in[(size_t)p.x * 256 + lane * 4];
        float w = __int_as_float(p.y);
        acc.x = fmaf(v.x, w, acc.x);
        acc.y = fmaf(v.y, w, acc.y);
        acc.z = fmaf(v.z, w, acc.z);
        acc.w = fmaf(v.w, w, acc.w);
    }
    *(float4*)&out[(size_t)node * 256 + lane * 4] = acc;
}

// ---------------- fp32 GEMM + bias + ReLU: C = relu(A[M,K] @ B[K,Nc] + bias) ----------------
// 128x128 tile, BK=16, 256 threads, 8x8 per thread (64 FMA per 4 ds_read_b128).
// K multiple of 16, Nc multiple of 128.

__global__ __launch_bounds__(256) void gemm_bias_relu(const float* __restrict__ A,
                                                      const float* __restrict__ B,
                                                      const float* __restrict__ bias,
                                                      float* __restrict__ C,
                                                      int M, int K, int Nc) {
    __shared__ float As[16][132];   // [k][m], +4 pad, float4-aligned
    __shared__ float Bs[16][128];   // [k][n]
    int tid = threadIdx.x;
    int bm = blockIdx.x * 128;
    int bn = blockIdx.y * 128;
    int tx = tid & 15;              // 0..15  -> col*8
    int ty = tid >> 4;              // 0..15  -> row*8

    int a_row = tid >> 1;           // 0..127
    int a_k = (tid & 1) * 8;        // 0 or 8
    int b_k = tid >> 4;             // 0..15
    int b_n = (tid & 15) * 8;       // 0..120

    float acc[8][8] = {};
    for (int k0 = 0; k0 < K; k0 += 16) {
        int gm = bm + a_row;
        float4 av0 = {0.f, 0.f, 0.f, 0.f}, av1 = {0.f, 0.f, 0.f, 0.f};
        if (gm < M) {
            const float* ap = &A[(size_t)gm * K + k0 + a_k];
            av0 = *(const float4*)ap;
            av1 = *(const float4*)(ap + 4);
        }
        As[a_k + 0][a_row] = av0.x;
        As[a_k + 1][a_row] = av0.y;
        As[a_k + 2][a_row] = av0.z;
        As[a_k + 3][a_row] = av0.w;
        As[a_k + 4][a_row] = av1.x;
        As[a_k + 5][a_row] = av1.y;
        As[a_k + 6][a_row] = av1.z;
        As[a_k + 7][a_row] = av1.w;
        const float* bp = &B[(size_t)(k0 + b_k) * Nc + bn + b_n];
        *(float4*)&Bs[b_k][b_n] = *(const float4*)bp;
        *(float4*)&Bs[b_k][b_n + 4] = *(const float4*)(bp + 4);
        __syncthreads();
        #pragma unroll
        for (int kk = 0; kk < 16; ++kk) {
            float a[8], b[8];
            *(float4*)&a[0] = *(const float4*)&As[kk][ty * 8];
            *(float4*)&a[4] = *(const float4*)&As[kk][ty * 8 + 4];
            *(float4*)&b[0] = *(const float4*)&Bs[kk][tx * 8];
            *(float4*)&b[4] = *(const float4*)&Bs[kk][tx * 8 + 4];
            #pragma unroll
            for (int i = 0; i < 8; ++i)
                #pragma unroll
                for (int j = 0; j < 8; ++j)
                    acc[i][j] = fmaf(a[i], b[j], acc[i][j]);
        }
        __syncthreads();
    }
    float bv[8];
    *(float4*)&bv[0] = *(const float4*)&bias[bn + tx * 8];
    *(float4*)&bv[4] = *(const float4*)&bias[bn + tx * 8 + 4];
    #pragma unroll
    for (int i = 0; i < 8; ++i) {
        int m = bm + ty * 8 + i;
        if (m < M) {
            float4 c0, c1;
            c0.x = fmaxf(acc[i][0] + bv[0], 0.f);
            c0.y = fmaxf(acc[i][1] + bv[1], 0.f);
            c0.z = fmaxf(acc[i][2] + bv[2], 0.f);
            c0.w = fmaxf(acc[i][3] + bv[3], 0.f);
            c1.x = fmaxf(acc[i][4] + bv[4], 0.f);
            c1.y = fmaxf(acc[i][5] + bv[5], 0.f);
            c1.z = fmaxf(acc[i][6] + bv[6], 0.f);
            c1.w = fmaxf(acc[i][7] + bv[7], 0.f);
            float* cp = &C[(size_t)m * Nc + bn + tx * 8];
            *(float4*)cp = c0;
            *(float4*)(cp + 4) = c1;
        }
    }
}

// ---------------- pool + head: one block per graph ----------------

__device__ __forceinline__ int lower_bound_i(const int* __restrict__ a, int n, int v) {
    int lo = 0, hi = n;
    while (lo < hi) {
        int mid = (lo + hi) >> 1;
        if (a[mid] < v) lo = mid + 1; else hi = mid;
    }
    return lo;
}

__global__ __launch_bounds__(256) void pool_head(const float* __restrict__ h,
                                                 const int* __restrict__ batch,
                                                 const float* __restrict__ num_atoms,
                                                 const float* __restrict__ W3, const float* __restrict__ b3,
                                                 const float* __restrict__ W4, const float* __restrict__ b4,
                                                 float* __restrict__ out, int n) {
    int g = blockIdx.x;
    int tid = threadIdx.x;
    __shared__ int s_lo, s_hi;
    if (tid == 0) {
        s_lo = lower_bound_i(batch, n, g);
        s_hi = lower_bound_i(batch, n, g + 1);
    }
    __syncthreads();
    int lo = s_lo, hi = s_hi;
    float sum = 0.f;
    for (int i = lo; i < hi; ++i) sum += h[(size_t)i * HDIM + tid];
    float cnt = (float)(hi - lo);
    float pooled = sum / fmaxf(cnt, 1.0f);

    __shared__ float zin[HDIM + 1];
    __shared__ float z[32];
    zin[tid] = pooled;
    if (tid == 0) zin[HDIM] = num_atoms[g];
    __syncthreads();
    if (tid < 32) {
        float a = b3[tid];
        for (int k = 0; k < HDIM + 1; ++k) a = fmaf(zin[k], W3[k * 32 + tid], a);
        z[tid] = fmaxf(a, 0.f);
    }
    __syncthreads();
    if (tid < 4) {
        float a = b4[tid];
        #pragma unroll
        for (int k = 0; k < 32; ++k) a = fmaf(z[k], W4[k * 4 + tid], a);
        out[g * 4 + tid] = a;
    }
}

// ---------------- launch ----------------

extern "C" void kernel_launch(void* const* d_in, const int* in_sizes, int n_in,
                              void* d_out, int out_size, void* d_ws, size_t ws_size,
                              hipStream_t stream) {
    const float* x         = (const float*)d_in[0];
    const int*   edge_idx  = (const int*)d_in[1];
    const int*   batch     = (const int*)d_in[2];
    const float* num_atoms = (const float*)d_in[3];
    const float* W1 = (const float*)d_in[4];
    const float* b1 = (const float*)d_in[5];
    const float* W2 = (const float*)d_in[6];
    const float* b2 = (const float*)d_in[7];
    const float* W3 = (const float*)d_in[8];
    const float* b3 = (const float*)d_in[9];
    const float* W4 = (const float*)d_in[10];
    const float* b4 = (const float*)d_in[11];
    float* out = (float*)d_out;

    const int n = NN, e = EE;
    const int* e_src = edge_idx;
    const int* e_dst = edge_idx + e;

    // workspace carve-out (256B aligned). Total ~110 MB.
    char* ws = (char*)d_ws;
    size_t off = 0;
    auto carve = [&](size_t bytes) -> void* {
        void* p = ws + off;
        off = (off + bytes + 255) & ~(size_t)255;
        return p;
    };
    int*   deg_i    = (int*)carve((size_t)n * 4);
    int*   row_off  = (int*)carve((size_t)(n + 1) * 4);
    int*   fill     = (int*)carve((size_t)n * 4);
    int*   blk_sums = (int*)carve((size_t)256 * 4);
    float* dinv     = (float*)carve((size_t)n * 4);
    int2*  csr      = (int2*)carve((size_t)e * 8);
    float* bufT     = (float*)carve((size_t)n * HDIM * 4);  // agg outputs (a0 aliased low half, a1 full)
    float* bufH     = (float*)carve((size_t)n * HDIM * 4);  // h1 then h2
    float* a0 = bufT;  // [N,128] alias — dead before agg256 writes bufT
    (void)ws_size; (void)n_in; (void)in_sizes; (void)out_size;

    hipMemsetAsync(deg_i, 0, (size_t)n * 4, stream);
    hist_kernel<<<1024, 256, 0, stream>>>(e_dst, deg_i, e);
    scan_part<<<SCAN_NB, 256, 0, stream>>>(deg_i, row_off, blk_sums, dinv, n);
    scan_sums<<<1, 256, 0, stream>>>(blk_sums, SCAN_NB);
    scan_add<<<SCAN_NB, 256, 0, stream>>>(row_off, blk_sums, fill, n, e);
    scatter_kernel<<<1024, 256, 0, stream>>>(e_src, e_dst, row_off, fill, dinv, csr, e);

    dim3 gemm_grid((n + 127) / 128, HDIM / 128);
    // layer 1: a0 = agg(x) [N,128]; h1 = relu(a0 @ W1 + b1) [N,256]
    gcn_agg128<<<(n + 3) / 4, 256, 0, stream>>>(x, row_off, csr, dinv, a0, n);
    gemm_bias_relu<<<gemm_grid, 256, 0, stream>>>(a0, W1, b1, bufH, n, FDIM, HDIM);
    // layer 2: a1 = agg(h1) [N,256]; h2 = relu(a1 @ W2 + b2) [N,256]
    gcn_agg256<<<(n + 3) / 4, 256, 0, stream>>>(bufH, row_off, csr, dinv, bufT, n);
    gemm_bias_relu<<<gemm_grid, 256, 0, stream>>>(bufT, W2, b2, bufH, n, HDIM, HDIM);
    // pool + head
    pool_head<<<GG, 256, 0, stream>>>(bufH, batch, num_atoms, W3, b3, W4, b4, out, n);
}

// Round 5
// 533.790 us; speedup vs baseline: 1.4568x; 1.0223x over previous
//
#include <hip/hip_runtime.h>
#include <hip/hip_bf16.h>

// GNN: 2-layer GCN (N=50000, E=800000, F=128, H=256) + mean-pool (G=512) + MLP head (257->32->4)
// Key identity: segment_sum((xW)[src]*norm) == (segment_sum(x[src]*norm)) @ W  (GCN agg is linear)
//   prep:  deg histogram -> hierarchical scan (dinv fused) -> packed CSR scatter (int2{src,w})
//   L1: agg128(x) -> a0 ; h1 = relu(a0 @ W1 + b1)
//   L2: agg256(h1) -> a1 ; h2 = relu(a1 @ W2 + b2)
//   head: per-graph block: binary-search node range in sorted batch, mean-pool, 257->32->4 MLP
// R3: hierarchical scan. R4: 128x128/8x8 GEMM, packed CSR.
// R5: agg latency fix — wave-uniform row bounds (readfirstlane), int4 CSR (2 edges/load),
//     software pipeline: prefetch next 4 CSR entries while 4 gathers are in flight.

#define NN 50000
#define EE 800000
#define FDIM 128
#define HDIM 256
#define GG 512
#define SCAN_NB ((NN + 255) / 256)   // 196 blocks, fits one 256-wide scan

// ---------------- prep kernels ----------------

__global__ void hist_kernel(const int* __restrict__ dst, int* __restrict__ deg, int e) {
    int i = blockIdx.x * blockDim.x + threadIdx.x;
    int stride = gridDim.x * blockDim.x;
    for (; i < e; i += stride) atomicAdd(&deg[dst[i]], 1);
}

__global__ __launch_bounds__(256) void scan_part(const int* __restrict__ deg,
                                                 int* __restrict__ row_off,
                                                 int* __restrict__ blk_sums,
                                                 float* __restrict__ dinv, int n) {
    __shared__ int s[256];
    int tid = threadIdx.x;
    int i = blockIdx.x * 256 + tid;
    int v = (i < n) ? deg[i] : 0;
    if (i < n) dinv[i] = rsqrtf((float)v + 1.0f);
    s[tid] = v;
    __syncthreads();
    #pragma unroll
    for (int off = 1; off < 256; off <<= 1) {
        int t = (tid >= off) ? s[tid - off] : 0;
        __syncthreads();
        s[tid] += t;
        __syncthreads();
    }
    if (i < n) row_off[i] = s[tid] - v;
    if (tid == 255) blk_sums[blockIdx.x] = s[255];
}

__global__ __launch_bounds__(256) void scan_sums(int* __restrict__ blk_sums, int nb) {
    __shared__ int s[256];
    int tid = threadIdx.x;
    int v = (tid < nb) ? blk_sums[tid] : 0;
    s[tid] = v;
    __syncthreads();
    #pragma unroll
    for (int off = 1; off < 256; off <<= 1) {
        int t = (tid >= off) ? s[tid - off] : 0;
        __syncthreads();
        s[tid] += t;
        __syncthreads();
    }
    if (tid < nb) blk_sums[tid] = s[tid] - v;
}

__global__ __launch_bounds__(256) void scan_add(int* __restrict__ row_off,
                                                const int* __restrict__ blk_sums,
                                                int* __restrict__ fill, int n, int e) {
    int i = blockIdx.x * 256 + threadIdx.x;
    if (i < n) {
        row_off[i] += blk_sums[blockIdx.x];
        fill[i] = 0;
    }
    if (i == 0) row_off[n] = e;
}

// packed CSR entry: .x = src node, .y = float bits of edge weight
__global__ void scatter_kernel(const int* __restrict__ src, const int* __restrict__ dst,
                               const int* __restrict__ row_off, int* __restrict__ fill,
                               const float* __restrict__ dinv,
                               int2* __restrict__ csr, int e) {
    int i = blockIdx.x * blockDim.x + threadIdx.x;
    int stride = gridDim.x * blockDim.x;
    for (; i < e; i += stride) {
        int s = src[i], d = dst[i];
        int pos = row_off[d] + atomicAdd(&fill[d], 1);
        csr[pos] = make_int2(s, __float_as_int(dinv[s] * dinv[d]));
    }
}

// ---------------- GCN aggregation: out[d] = sum_e in[src_e]*w_e + in[d]*dinv[d]^2 ----------------
// one wave per node; wave-uniform bounds, int4 CSR loads, 4-deep gather pipeline

__global__ __launch_bounds__(256) void gcn_agg256(const float* __restrict__ in,
                                                  const int* __restrict__ row_off,
                                                  const int2* __restrict__ csr,
                                                  const float* __restrict__ dinv,
                                                  float* __restrict__ out, int n) {
    int wave = threadIdx.x >> 6;
    int lane = threadIdx.x & 63;
    int node = blockIdx.x * 4 + wave;
    if (node >= n) return;
    float di = dinv[node];
    float w0 = di * di;
    float4 hv = *(const float4*)&in[(size_t)node * 256 + lane * 4];
    float4 acc = {hv.x * w0, hv.y * w0, hv.z * w0, hv.w * w0};
    int beg = __builtin_amdgcn_readfirstlane(row_off[node]);
    int end = __builtin_amdgcn_readfirstlane(row_off[node + 1]);
    int e = beg;
    if ((e & 1) && e < end) {   // align to even index for int4 loads
        int2 p = csr[e];
        float4 v = *(const float4*)&in[(size_t)p.x * 256 + lane * 4];
        float w = __int_as_float(p.y);
        acc.x = fmaf(v.x, w, acc.x);
        acc.y = fmaf(v.y, w, acc.y);
        acc.z = fmaf(v.z, w, acc.z);
        acc.w = fmaf(v.w, w, acc.w);
        ++e;
    }
    int nmain = (end - e) >> 2;
    if (nmain > 0) {
        const int4* cp = (const int4*)&csr[e];   // 16B-aligned (e even, base 256B-aligned)
        int4 q0 = cp[0], q1 = cp[1];
        for (int it = 1; it < nmain; ++it) {
            int4 r0 = cp[2 * it], r1 = cp[2 * it + 1];   // prefetch next chunk
            float4 v0 = *(const float4*)&in[(size_t)q0.x * 256 + lane * 4];
            float4 v1 = *(const float4*)&in[(size_t)q0.z * 256 + lane * 4];
            float4 v2 = *(const float4*)&in[(size_t)q1.x * 256 + lane * 4];
            float4 v3 = *(const float4*)&in[(size_t)q1.z * 256 + lane * 4];
            float wa = __int_as_float(q0.y), wb = __int_as_float(q0.w);
            float wc = __int_as_float(q1.y), wd = __int_as_float(q1.w);
            acc.x = fmaf(v0.x, wa, acc.x); acc.y = fmaf(v0.y, wa, acc.y);
            acc.z = fmaf(v0.z, wa, acc.z); acc.w = fmaf(v0.w, wa, acc.w);
            acc.x = fmaf(v1.x, wb, acc.x); acc.y = fmaf(v1.y, wb, acc.y);
            acc.z = fmaf(v1.z, wb, acc.z); acc.w = fmaf(v1.w, wb, acc.w);
            acc.x = fmaf(v2.x, wc, acc.x); acc.y = fmaf(v2.y, wc, acc.y);
            acc.z = fmaf(v2.z, wc, acc.z); acc.w = fmaf(v2.w, wc, acc.w);
            acc.x = fmaf(v3.x, wd, acc.x); acc.y = fmaf(v3.y, wd, acc.y);
            acc.z = fmaf(v3.z, wd, acc.z); acc.w = fmaf(v3.w, wd, acc.w);
            q0 = r0; q1 = r1;
        }
        {
            float4 v0 = *(const float4*)&in[(size_t)q0.x * 256 + lane * 4];
            float4 v1 = *(const float4*)&in[(size_t)q0.z * 256 + lane * 4];
            float4 v2 = *(const float4*)&in[(size_t)q1.x * 256 + lane * 4];
            float4 v3 = *(const float4*)&in[(size_t)q1.z * 256 + lane * 4];
            float wa = __int_as_float(q0.y), wb = __int_as_float(q0.w);
            float wc = __int_as_float(q1.y), wd = __int_as_float(q1.w);
            acc.x = fmaf(v0.x, wa, acc.x); acc.y = fmaf(v0.y, wa, acc.y);
            acc.z = fmaf(v0.z, wa, acc.z); acc.w = fmaf(v0.w, wa, acc.w);
            acc.x = fmaf(v1.x, wb, acc.x); acc.y = fmaf(v1.y, wb, acc.y);
            acc.z = fmaf(v1.z, wb, acc.z); acc.w = fmaf(v1.w, wb, acc.w);
            acc.x = fmaf(v2.x, wc, acc.x); acc.y = fmaf(v2.y, wc, acc.y);
            acc.z = fmaf(v2.z, wc, acc.z); acc.w = fmaf(v2.w, wc, acc.w);
            acc.x = fmaf(v3.x, wd, acc.x); acc.y = fmaf(v3.y, wd, acc.y);
            acc.z = fmaf(v3.z, wd, acc.z); acc.w = fmaf(v3.w, wd, acc.w);
        }
        e += nmain * 4;
    }
    for (; e < end; ++e) {
        int2 p = csr[e];
        float4 v = *(const float4*)&in[(size_t)p.x * 256 + lane * 4];
        float w = __int_as_float(p.y);
        acc.x = fmaf(v.x, w, acc.x);
        acc.y = fmaf(v.y, w, acc.y);
        acc.z = fmaf(v.z, w, acc.z);
        acc.w = fmaf(v.w, w, acc.w);
    }
    *(float4*)&out[(size_t)node * 256 + lane * 4] = acc;
}

__global__ __launch_bounds__(256) void gcn_agg128(const float* __restrict__ in,
                                                  const int* __restrict__ row_off,
                                                  const int2* __restrict__ csr,
                                                  const float* __restrict__ dinv,
                                                  float* __restrict__ out, int n) {
    int wave = threadIdx.x >> 6;
    int lane = threadIdx.x & 63;
    int node = blockIdx.x * 4 + wave;
    if (node >= n) return;
    float di = dinv[node];
    float w0 = di * di;
    float2 hv = *(const float2*)&in[(size_t)node * 128 + lane * 2];
    float2 acc = {hv.x * w0, hv.y * w0};
    int beg = __builtin_amdgcn_readfirstlane(row_off[node]);
    int end = __builtin_amdgcn_readfirstlane(row_off[node + 1]);
    int e = beg;
    if ((e & 1) && e < end) {
        int2 p = csr[e];
        float2 v = *(const float2*)&in[(size_t)p.x * 128 + lane * 2];
        float w = __int_as_float(p.y);
        acc.x = fmaf(v.x, w, acc.x);
        acc.y = fmaf(v.y, w, acc.y);
        ++e;
    }
    int nmain = (end - e) >> 2;
    if (nmain > 0) {
        const int4* cp = (const int4*)&csr[e];
        int4 q0 = cp[0], q1 = cp[1];
        for (int it = 1; it < nmain; ++it) {
            int4 r0 = cp[2 * it], r1 = cp[2 * it + 1];
            float2 v0 = *(const float2*)&in[(size_t)q0.x * 128 + lane * 2];
            float2 v1 = *(const float2*)&in[(size_t)q0.z * 128 + lane * 2];
            float2 v2 = *(const float2*)&in[(size_t)q1.x * 128 + lane * 2];
            float2 v3 = *(const float2*)&in[(size_t)q1.z * 128 + lane * 2];
            float wa = __int_as_float(q0.y), wb = __int_as_float(q0.w);
            float wc = __int_as_float(q1.y), wd = __int_as_float(q1.w);
            acc.x = fmaf(v0.x, wa, acc.x); acc.y = fmaf(v0.y, wa, acc.y);
            acc.x = fmaf(v1.x, wb, acc.x); acc.y = fmaf(v1.y, wb, acc.y);
            acc.x = fmaf(v2.x, wc, acc.x); acc.y = fmaf(v2.y, wc, acc.y);
            acc.x = fmaf(v3.x, wd, acc.x); acc.y = fmaf(v3.y, wd, acc.y);
            q0 = r0; q1 = r1;
        }
        {
            float2 v0 = *(const float2*)&in[(size_t)q0.x * 128 + lane * 2];
            float2 v1 = *(const float2*)&in[(size_t)q0.z * 128 + lane * 2];
            float2 v2 = *(const float2*)&in[(size_t)q1.x * 128 + lane * 2];
            float2 v3 = *(const float2*)&in[(size_t)q1.z * 128 + lane * 2];
            float wa = __int_as_float(q0.y), wb = __int_as_float(q0.w);
            float wc = __int_as_float(q1.y), wd = __int_as_float(q1.w);
            acc.x = fmaf(v0.x, wa, acc.x); acc.y = fmaf(v0.y, wa, acc.y);
            acc.x = fmaf(v1.x, wb, acc.x); acc.y = fmaf(v1.y, wb, acc.y);
            acc.x = fmaf(v2.x, wc, acc.x); acc.y = fmaf(v2.y, wc, acc.y);
            acc.x = fmaf(v3.x, wd, acc.x); acc.y = fmaf(v3.y, wd, acc.y);
        }
        e += nmain * 4;
    }
    for (; e < end; ++e) {
        int2 p = csr[e];
        float2 v = *(const float2*)&in[(size_t)p.x * 128 + lane * 2];
        float w = __int_as_float(p.y);
        acc.x = fmaf(v.x, w, acc.x);
        acc.y = fmaf(v.y, w, acc.y);
    }
    *(float2*)&out[(size_t)node * 128 + lane * 2] = acc;
}

// ---------------- fp32 GEMM + bias + ReLU: C = relu(A[M,K] @ B[K,Nc] + bias) ----------------
// 128x128 tile, BK=16, 256 threads, 8x8 per thread. K mult of 16, Nc mult of 128.

__global__ __launch_bounds__(256) void gemm_bias_relu(const float* __restrict__ A,
                                                      const float* __restrict__ B,
                                                      const float* __restrict__ bias,
                                                      float* __restrict__ C,
                                                      int M, int K, int Nc) {
    __shared__ float As[16][132];
    __shared__ float Bs[16][128];
    int tid = threadIdx.x;
    int bm = blockIdx.x * 128;
    int bn = blockIdx.y * 128;
    int tx = tid & 15;
    int ty = tid >> 4;

    int a_row = tid >> 1;
    int a_k = (tid & 1) * 8;
    int b_k = tid >> 4;
    int b_n = (tid & 15) * 8;

    float acc[8][8] = {};
    for (int k0 = 0; k0 < K; k0 += 16) {
        int gm = bm + a_row;
        float4 av0 = {0.f, 0.f, 0.f, 0.f}, av1 = {0.f, 0.f, 0.f, 0.f};
        if (gm < M) {
            const float* ap = &A[(size_t)gm * K + k0 + a_k];
            av0 = *(const float4*)ap;
            av1 = *(const float4*)(ap + 4);
        }
        As[a_k + 0][a_row] = av0.x;
        As[a_k + 1][a_row] = av0.y;
        As[a_k + 2][a_row] = av0.z;
        As[a_k + 3][a_row] = av0.w;
        As[a_k + 4][a_row] = av1.x;
        As[a_k + 5][a_row] = av1.y;
        As[a_k + 6][a_row] = av1.z;
        As[a_k + 7][a_row] = av1.w;
        const float* bp = &B[(size_t)(k0 + b_k) * Nc + bn + b_n];
        *(float4*)&Bs[b_k][b_n] = *(const float4*)bp;
        *(float4*)&Bs[b_k][b_n + 4] = *(const float4*)(bp + 4);
        __syncthreads();
        #pragma unroll
        for (int kk = 0; kk < 16; ++kk) {
            float a[8], b[8];
            *(float4*)&a[0] = *(const float4*)&As[kk][ty * 8];
            *(float4*)&a[4] = *(const float4*)&As[kk][ty * 8 + 4];
            *(float4*)&b[0] = *(const float4*)&Bs[kk][tx * 8];
            *(float4*)&b[4] = *(const float4*)&Bs[kk][tx * 8 + 4];
            #pragma unroll
            for (int i = 0; i < 8; ++i)
                #pragma unroll
                for (int j = 0; j < 8; ++j)
                    acc[i][j] = fmaf(a[i], b[j], acc[i][j]);
        }
        __syncthreads();
    }
    float bv[8];
    *(float4*)&bv[0] = *(const float4*)&bias[bn + tx * 8];
    *(float4*)&bv[4] = *(const float4*)&bias[bn + tx * 8 + 4];
    #pragma unroll
    for (int i = 0; i < 8; ++i) {
        int m = bm + ty * 8 + i;
        if (m < M) {
            float4 c0, c1;
            c0.x = fmaxf(acc[i][0] + bv[0], 0.f);
            c0.y = fmaxf(acc[i][1] + bv[1], 0.f);
            c0.z = fmaxf(acc[i][2] + bv[2], 0.f);
            c0.w = fmaxf(acc[i][3] + bv[3], 0.f);
            c1.x = fmaxf(acc[i][4] + bv[4], 0.f);
            c1.y = fmaxf(acc[i][5] + bv[5], 0.f);
            c1.z = fmaxf(acc[i][6] + bv[6], 0.f);
            c1.w = fmaxf(acc[i][7] + bv[7], 0.f);
            float* cp = &C[(size_t)m * Nc + bn + tx * 8];
            *(float4*)cp = c0;
            *(float4*)(cp + 4) = c1;
        }
    }
}

// ---------------- pool + head: one block per graph ----------------

__device__ __forceinline__ int lower_bound_i(const int* __restrict__ a, int n, int v) {
    int lo = 0, hi = n;
    while (lo < hi) {
        int mid = (lo + hi) >> 1;
        if (a[mid] < v) lo = mid + 1; else hi = mid;
    }
    return lo;
}

__global__ __launch_bounds__(256) void pool_head(const float* __restrict__ h,
                                                 const int* __restrict__ batch,
                                                 const float* __restrict__ num_atoms,
                                                 const float* __restrict__ W3, const float* __restrict__ b3,
                                                 const float* __restrict__ W4, const float* __restrict__ b4,
                                                 float* __restrict__ out, int n) {
    int g = blockIdx.x;
    int tid = threadIdx.x;
    __shared__ int s_lo, s_hi;
    if (tid == 0) {
        s_lo = lower_bound_i(batch, n, g);
        s_hi = lower_bound_i(batch, n, g + 1);
    }
    __syncthreads();
    int lo = s_lo, hi = s_hi;
    float sum = 0.f;
    for (int i = lo; i < hi; ++i) sum += h[(size_t)i * HDIM + tid];
    float cnt = (float)(hi - lo);
    float pooled = sum / fmaxf(cnt, 1.0f);

    __shared__ float zin[HDIM + 1];
    __shared__ float z[32];
    zin[tid] = pooled;
    if (tid == 0) zin[HDIM] = num_atoms[g];
    __syncthreads();
    if (tid < 32) {
        float a = b3[tid];
        for (int k = 0; k < HDIM + 1; ++k) a = fmaf(zin[k], W3[k * 32 + tid], a);
        z[tid] = fmaxf(a, 0.f);
    }
    __syncthreads();
    if (tid < 4) {
        float a = b4[tid];
        #pragma unroll
        for (int k = 0; k < 32; ++k) a = fmaf(z[k], W4[k * 4 + tid], a);
        out[g * 4 + tid] = a;
    }
}

// ---------------- launch ----------------

extern "C" void kernel_launch(void* const* d_in, const int* in_sizes, int n_in,
                              void* d_out, int out_size, void* d_ws, size_t ws_size,
                              hipStream_t stream) {
    const float* x         = (const float*)d_in[0];
    const int*   edge_idx  = (const int*)d_in[1];
    const int*   batch     = (const int*)d_in[2];
    const float* num_atoms = (const float*)d_in[3];
    const float* W1 = (const float*)d_in[4];
    const float* b1 = (const float*)d_in[5];
    const float* W2 = (const float*)d_in[6];
    const float* b2 = (const float*)d_in[7];
    const float* W3 = (const float*)d_in[8];
    const float* b3 = (const float*)d_in[9];
    const float* W4 = (const float*)d_in[10];
    const float* b4 = (const float*)d_in[11];
    float* out = (float*)d_out;

    const int n = NN, e = EE;
    const int* e_src = edge_idx;
    const int* e_dst = edge_idx + e;

    char* ws = (char*)d_ws;
    size_t off = 0;
    auto carve = [&](size_t bytes) -> void* {
        void* p = ws + off;
        off = (off + bytes + 255) & ~(size_t)255;
        return p;
    };
    int*   deg_i    = (int*)carve((size_t)n * 4);
    int*   row_off  = (int*)carve((size_t)(n + 1) * 4);
    int*   fill     = (int*)carve((size_t)n * 4);
    int*   blk_sums = (int*)carve((size_t)256 * 4);
    float* dinv     = (float*)carve((size_t)n * 4);
    int2*  csr      = (int2*)carve((size_t)e * 8);
    float* bufT     = (float*)carve((size_t)n * HDIM * 4);
    float* bufH     = (float*)carve((size_t)n * HDIM * 4);
    float* a0 = bufT;  // [N,128] alias — dead before agg256 writes bufT
    (void)ws_size; (void)n_in; (void)in_sizes; (void)out_size;

    hipMemsetAsync(deg_i, 0, (size_t)n * 4, stream);
    hist_kernel<<<1024, 256, 0, stream>>>(e_dst, deg_i, e);
    scan_part<<<SCAN_NB, 256, 0, stream>>>(deg_i, row_off, blk_sums, dinv, n);
    scan_sums<<<1, 256, 0, stream>>>(blk_sums, SCAN_NB);
    scan_add<<<SCAN_NB, 256, 0, stream>>>(row_off, blk_sums, fill, n, e);
    scatter_kernel<<<1024, 256, 0, stream>>>(e_src, e_dst, row_off, fill, dinv, csr, e);

    dim3 gemm_grid((n + 127) / 128, HDIM / 128);
    gcn_agg128<<<(n + 3) / 4, 256, 0, stream>>>(x, row_off, csr, dinv, a0, n);
    gemm_bias_relu<<<gemm_grid, 256, 0, stream>>>(a0, W1, b1, bufH, n, FDIM, HDIM);
    gcn_agg256<<<(n + 3) / 4, 256, 0, stream>>>(bufH, row_off, csr, dinv, bufT, n);
    gemm_bias_relu<<<gemm_grid, 256, 0, stream>>>(bufT, W2, b2, bufH, n, HDIM, HDIM);
    pool_head<<<GG, 256, 0, stream>>>(bufH, batch, num_atoms, W3, b3, W4, b4, out, n);
}

// Round 6
// 461.818 us; speedup vs baseline: 1.6838x; 1.1558x over previous
//
#include <hip/hip_runtime.h>
#include <hip/hip_bf16.h>

// GNN: 2-layer GCN (N=50000, E=800000, F=128, H=256) + mean-pool (G=512) + MLP head (257->32->4)
// Key identity: segment_sum((xW)[src]*norm) == (segment_sum(x[src]*norm)) @ W  (GCN agg is linear)
//   prep:  deg histogram -> hierarchical scan (dinv fused) -> packed CSR scatter (int2{src,w})
//   L1: cast x->bf16; agg128_bf16 -> a0 (fp32); h1b = relu(a0 @ W1 + b1) written as bf16
//   L2: agg256_bf16(h1b) -> a1 (fp32); h2 = relu(a1 @ W2 + b2) fp32
//   head: per-graph block: binary-search node range in sorted batch, mean-pool, 257->32->4 MLP
// R5 evidence: agg256 is L2-miss-path bound (402MB fetch for 51MB input = 8x XCD amplification,
// 3.7 TB/s, VALUBusy 4%). R6: halve gathered bytes via bf16 payloads; accumulate fp32.

#define NN 50000
#define EE 800000
#define FDIM 128
#define HDIM 256
#define GG 512
#define SCAN_NB ((NN + 255) / 256)

typedef __attribute__((ext_vector_type(8))) unsigned short ushort8;

__device__ __forceinline__ unsigned short f2bf(float f) {   // RNE
    unsigned u = __float_as_uint(f);
    return (unsigned short)((u + 0x7FFF + ((u >> 16) & 1)) >> 16);
}
__device__ __forceinline__ float bflo(unsigned v) { return __uint_as_float(v << 16); }
__device__ __forceinline__ float bfhi(unsigned v) { return __uint_as_float(v & 0xFFFF0000u); }

// ---------------- prep kernels ----------------

__global__ void hist_kernel(const int* __restrict__ dst, int* __restrict__ deg, int e) {
    int i = blockIdx.x * blockDim.x + threadIdx.x;
    int stride = gridDim.x * blockDim.x;
    for (; i < e; i += stride) atomicAdd(&deg[dst[i]], 1);
}

__global__ __launch_bounds__(256) void scan_part(const int* __restrict__ deg,
                                                 int* __restrict__ row_off,
                                                 int* __restrict__ blk_sums,
                                                 float* __restrict__ dinv, int n) {
    __shared__ int s[256];
    int tid = threadIdx.x;
    int i = blockIdx.x * 256 + tid;
    int v = (i < n) ? deg[i] : 0;
    if (i < n) dinv[i] = rsqrtf((float)v + 1.0f);
    s[tid] = v;
    __syncthreads();
    #pragma unroll
    for (int off = 1; off < 256; off <<= 1) {
        int t = (tid >= off) ? s[tid - off] : 0;
        __syncthreads();
        s[tid] += t;
        __syncthreads();
    }
    if (i < n) row_off[i] = s[tid] - v;
    if (tid == 255) blk_sums[blockIdx.x] = s[255];
}

__global__ __launch_bounds__(256) void scan_sums(int* __restrict__ blk_sums, int nb) {
    __shared__ int s[256];
    int tid = threadIdx.x;
    int v = (tid < nb) ? blk_sums[tid] : 0;
    s[tid] = v;
    __syncthreads();
    #pragma unroll
    for (int off = 1; off < 256; off <<= 1) {
        int t = (tid >= off) ? s[tid - off] : 0;
        __syncthreads();
        s[tid] += t;
        __syncthreads();
    }
    if (tid < nb) blk_sums[tid] = s[tid] - v;
}

__global__ __launch_bounds__(256) void scan_add(int* __restrict__ row_off,
                                                const int* __restrict__ blk_sums,
                                                int* __restrict__ fill, int n, int e) {
    int i = blockIdx.x * 256 + threadIdx.x;
    if (i < n) {
        row_off[i] += blk_sums[blockIdx.x];
        fill[i] = 0;
    }
    if (i == 0) row_off[n] = e;
}

__global__ void scatter_kernel(const int* __restrict__ src, const int* __restrict__ dst,
                               const int* __restrict__ row_off, int* __restrict__ fill,
                               const float* __restrict__ dinv,
                               int2* __restrict__ csr, int e) {
    int i = blockIdx.x * blockDim.x + threadIdx.x;
    int stride = gridDim.x * blockDim.x;
    for (; i < e; i += stride) {
        int s = src[i], d = dst[i];
        int pos = row_off[d] + atomicAdd(&fill[d], 1);
        csr[pos] = make_int2(s, __float_as_int(dinv[s] * dinv[d]));
    }
}

// fp32 -> bf16 cast, vectorized (count multiple of 4)
__global__ void cast_f32_bf16(const float* __restrict__ in, unsigned short* __restrict__ out,
                              int count) {
    int i = (blockIdx.x * blockDim.x + threadIdx.x) * 4;
    int stride = gridDim.x * blockDim.x * 4;
    for (; i < count; i += stride) {
        float4 v = *(const float4*)&in[i];
        ushort4 o;
        o.x = f2bf(v.x); o.y = f2bf(v.y); o.z = f2bf(v.z); o.w = f2bf(v.w);
        *(ushort4*)&out[i] = o;
    }
}

// ---------------- GCN aggregation (bf16 payload, fp32 accumulate) ----------------
// out[d] = sum_e in[src_e]*w_e + in[d]*dinv[d]^2
// one wave per node; wave-uniform bounds, int4 CSR loads, 4-deep gather pipeline

__global__ __launch_bounds__(256) void gcn_agg256_bf16(const unsigned short* __restrict__ in,
                                                       const int* __restrict__ row_off,
                                                       const int2* __restrict__ csr,
                                                       const float* __restrict__ dinv,
                                                       float* __restrict__ out, int n) {
    int wave = threadIdx.x >> 6;
    int lane = threadIdx.x & 63;
    int node = blockIdx.x * 4 + wave;
    if (node >= n) return;
    float di = dinv[node];
    float w0 = di * di;
    uint2 hu = *(const uint2*)&in[(size_t)node * 256 + lane * 4];
    float4 acc;
    acc.x = bflo(hu.x) * w0; acc.y = bfhi(hu.x) * w0;
    acc.z = bflo(hu.y) * w0; acc.w = bfhi(hu.y) * w0;
    int beg = __builtin_amdgcn_readfirstlane(row_off[node]);
    int end = __builtin_amdgcn_readfirstlane(row_off[node + 1]);
    int e = beg;
    if ((e & 1) && e < end) {
        int2 p = csr[e];
        uint2 u = *(const uint2*)&in[(size_t)p.x * 256 + lane * 4];
        float w = __int_as_float(p.y);
        acc.x = fmaf(bflo(u.x), w, acc.x); acc.y = fmaf(bfhi(u.x), w, acc.y);
        acc.z = fmaf(bflo(u.y), w, acc.z); acc.w = fmaf(bfhi(u.y), w, acc.w);
        ++e;
    }
    int nmain = (end - e) >> 2;
    if (nmain > 0) {
        const int4* cp = (const int4*)&csr[e];
        int4 q0 = cp[0], q1 = cp[1];
        for (int it = 1; it < nmain; ++it) {
            int4 r0 = cp[2 * it], r1 = cp[2 * it + 1];
            uint2 u0 = *(const uint2*)&in[(size_t)q0.x * 256 + lane * 4];
            uint2 u1 = *(const uint2*)&in[(size_t)q0.z * 256 + lane * 4];
            uint2 u2 = *(const uint2*)&in[(size_t)q1.x * 256 + lane * 4];
            uint2 u3 = *(const uint2*)&in[(size_t)q1.z * 256 + lane * 4];
            float wa = __int_as_float(q0.y), wb = __int_as_float(q0.w);
            float wc = __int_as_float(q1.y), wd = __int_as_float(q1.w);
            acc.x = fmaf(bflo(u0.x), wa, acc.x); acc.y = fmaf(bfhi(u0.x), wa, acc.y);
            acc.z = fmaf(bflo(u0.y), wa, acc.z); acc.w = fmaf(bfhi(u0.y), wa, acc.w);
            acc.x = fmaf(bflo(u1.x), wb, acc.x); acc.y = fmaf(bfhi(u1.x), wb, acc.y);
            acc.z = fmaf(bflo(u1.y), wb, acc.z); acc.w = fmaf(bfhi(u1.y), wb, acc.w);
            acc.x = fmaf(bflo(u2.x), wc, acc.x); acc.y = fmaf(bfhi(u2.x), wc, acc.y);
            acc.z = fmaf(bflo(u2.y), wc, acc.z); acc.w = fmaf(bfhi(u2.y), wc, acc.w);
            acc.x = fmaf(bflo(u3.x), wd, acc.x); acc.y = fmaf(bfhi(u3.x), wd, acc.y);
            acc.z = fmaf(bflo(u3.y), wd, acc.z); acc.w = fmaf(bfhi(u3.y), wd, acc.w);
            q0 = r0; q1 = r1;
        }
        {
            uint2 u0 = *(const uint2*)&in[(size_t)q0.x * 256 + lane * 4];
            uint2 u1 = *(const uint2*)&in[(size_t)q0.z * 256 + lane * 4];
            uint2 u2 = *(const uint2*)&in[(size_t)q1.x * 256 + lane * 4];
            uint2 u3 = *(const uint2*)&in[(size_t)q1.z * 256 + lane * 4];
            float wa = __int_as_float(q0.y), wb = __int_as_float(q0.w);
            float wc = __int_as_float(q1.y), wd = __int_as_float(q1.w);
            acc.x = fmaf(bflo(u0.x), wa, acc.x); acc.y = fmaf(bfhi(u0.x), wa, acc.y);
            acc.z = fmaf(bflo(u0.y), wa, acc.z); acc.w = fmaf(bfhi(u0.y), wa, acc.w);
            acc.x = fmaf(bflo(u1.x), wb, acc.x); acc.y = fmaf(bfhi(u1.x), wb, acc.y);
            acc.z = fmaf(bflo(u1.y), wb, acc.z); acc.w = fmaf(bfhi(u1.y), wb, acc.w);
            acc.x = fmaf(bflo(u2.x), wc, acc.x); acc.y = fmaf(bfhi(u2.x), wc, acc.y);
            acc.z = fmaf(bflo(u2.y), wc, acc.z); acc.w = fmaf(bfhi(u2.y), wc, acc.w);
            acc.x = fmaf(bflo(u3.x), wd, acc.x); acc.y = fmaf(bfhi(u3.x), wd, acc.y);
            acc.z = fmaf(bflo(u3.y), wd, acc.z); acc.w = fmaf(bfhi(u3.y), wd, acc.w);
        }
        e += nmain * 4;
    }
    for (; e < end; ++e) {
        int2 p = csr[e];
        uint2 u = *(const uint2*)&in[(size_t)p.x * 256 + lane * 4];
        float w = __int_as_float(p.y);
        acc.x = fmaf(bflo(u.x), w, acc.x); acc.y = fmaf(bfhi(u.x), w, acc.y);
        acc.z = fmaf(bflo(u.y), w, acc.z); acc.w = fmaf(bfhi(u.y), w, acc.w);
    }
    *(float4*)&out[(size_t)node * 256 + lane * 4] = acc;
}

__global__ __launch_bounds__(256) void gcn_agg128_bf16(const unsigned short* __restrict__ in,
                                                       const int* __restrict__ row_off,
                                                       const int2* __restrict__ csr,
                                                       const float* __restrict__ dinv,
                                                       float* __restrict__ out, int n) {
    int wave = threadIdx.x >> 6;
    int lane = threadIdx.x & 63;
    int node = blockIdx.x * 4 + wave;
    if (node >= n) return;
    float di = dinv[node];
    float w0 = di * di;
    unsigned hu = *(const unsigned*)&in[(size_t)node * 128 + lane * 2];
    float2 acc = {bflo(hu) * w0, bfhi(hu) * w0};
    int beg = __builtin_amdgcn_readfirstlane(row_off[node]);
    int end = __builtin_amdgcn_readfirstlane(row_off[node + 1]);
    int e = beg;
    if ((e & 1) && e < end) {
        int2 p = csr[e];
        unsigned u = *(const unsigned*)&in[(size_t)p.x * 128 + lane * 2];
        float w = __int_as_float(p.y);
        acc.x = fmaf(bflo(u), w, acc.x);
        acc.y = fmaf(bfhi(u), w, acc.y);
        ++e;
    }
    int nmain = (end - e) >> 2;
    if (nmain > 0) {
        const int4* cp = (const int4*)&csr[e];
        int4 q0 = cp[0], q1 = cp[1];
        for (int it = 1; it < nmain; ++it) {
            int4 r0 = cp[2 * it], r1 = cp[2 * it + 1];
            unsigned u0 = *(const unsigned*)&in[(size_t)q0.x * 128 + lane * 2];
            unsigned u1 = *(const unsigned*)&in[(size_t)q0.z * 128 + lane * 2];
            unsigned u2 = *(const unsigned*)&in[(size_t)q1.x * 128 + lane * 2];
            unsigned u3 = *(const unsigned*)&in[(size_t)q1.z * 128 + lane * 2];
            float wa = __int_as_float(q0.y), wb = __int_as_float(q0.w);
            float wc = __int_as_float(q1.y), wd = __int_as_float(q1.w);
            acc.x = fmaf(bflo(u0), wa, acc.x); acc.y = fmaf(bfhi(u0), wa, acc.y);
            acc.x = fmaf(bflo(u1), wb, acc.x); acc.y = fmaf(bfhi(u1), wb, acc.y);
            acc.x = fmaf(bflo(u2), wc, acc.x); acc.y = fmaf(bfhi(u2), wc, acc.y);
            acc.x = fmaf(bflo(u3), wd, acc.x); acc.y = fmaf(bfhi(u3), wd, acc.y);
            q0 = r0; q1 = r1;
        }
        {
            unsigned u0 = *(const unsigned*)&in[(size_t)q0.x * 128 + lane * 2];
            unsigned u1 = *(const unsigned*)&in[(size_t)q0.z * 128 + lane * 2];
            unsigned u2 = *(const unsigned*)&in[(size_t)q1.x * 128 + lane * 2];
            unsigned u3 = *(const unsigned*)&in[(size_t)q1.z * 128 + lane * 2];
            float wa = __int_as_float(q0.y), wb = __int_as_float(q0.w);
            float wc = __int_as_float(q1.y), wd = __int_as_float(q1.w);
            acc.x = fmaf(bflo(u0), wa, acc.x); acc.y = fmaf(bfhi(u0), wa, acc.y);
            acc.x = fmaf(bflo(u1), wb, acc.x); acc.y = fmaf(bfhi(u1), wb, acc.y);
            acc.x = fmaf(bflo(u2), wc, acc.x); acc.y = fmaf(bfhi(u2), wc, acc.y);
            acc.x = fmaf(bflo(u3), wd, acc.x); acc.y = fmaf(bfhi(u3), wd, acc.y);
        }
        e += nmain * 4;
    }
    for (; e < end; ++e) {
        int2 p = csr[e];
        unsigned u = *(const unsigned*)&in[(size_t)p.x * 128 + lane * 2];
        float w = __int_as_float(p.y);
        acc.x = fmaf(bflo(u), w, acc.x);
        acc.y = fmaf(bfhi(u), w, acc.y);
    }
    *(float2*)&out[(size_t)node * 128 + lane * 2] = acc;
}

// ---------------- fp32 GEMM + bias + ReLU: C = relu(A[M,K] @ B[K,Nc] + bias) ----------------
// 128x128 tile, BK=16, 256 threads, 8x8 per thread. K mult of 16, Nc mult of 128.
// BF16_OUT: epilogue converts to bf16 (RNE).

template<bool BF16_OUT>
__global__ __launch_bounds__(256) void gemm_bias_relu(const float* __restrict__ A,
                                                      const float* __restrict__ B,
                                                      const float* __restrict__ bias,
                                                      void* __restrict__ Cv,
                                                      int M, int K, int Nc) {
    __shared__ float As[16][132];
    __shared__ float Bs[16][128];
    int tid = threadIdx.x;
    int bm = blockIdx.x * 128;
    int bn = blockIdx.y * 128;
    int tx = tid & 15;
    int ty = tid >> 4;

    int a_row = tid >> 1;
    int a_k = (tid & 1) * 8;
    int b_k = tid >> 4;
    int b_n = (tid & 15) * 8;

    float acc[8][8] = {};
    for (int k0 = 0; k0 < K; k0 += 16) {
        int gm = bm + a_row;
        float4 av0 = {0.f, 0.f, 0.f, 0.f}, av1 = {0.f, 0.f, 0.f, 0.f};
        if (gm < M) {
            const float* ap = &A[(size_t)gm * K + k0 + a_k];
            av0 = *(const float4*)ap;
            av1 = *(const float4*)(ap + 4);
        }
        As[a_k + 0][a_row] = av0.x;
        As[a_k + 1][a_row] = av0.y;
        As[a_k + 2][a_row] = av0.z;
        As[a_k + 3][a_row] = av0.w;
        As[a_k + 4][a_row] = av1.x;
        As[a_k + 5][a_row] = av1.y;
        As[a_k + 6][a_row] = av1.z;
        As[a_k + 7][a_row] = av1.w;
        const float* bp = &B[(size_t)(k0 + b_k) * Nc + bn + b_n];
        *(float4*)&Bs[b_k][b_n] = *(const float4*)bp;
        *(float4*)&Bs[b_k][b_n + 4] = *(const float4*)(bp + 4);
        __syncthreads();
        #pragma unroll
        for (int kk = 0; kk < 16; ++kk) {
            float a[8], b[8];
            *(float4*)&a[0] = *(const float4*)&As[kk][ty * 8];
            *(float4*)&a[4] = *(const float4*)&As[kk][ty * 8 + 4];
            *(float4*)&b[0] = *(const float4*)&Bs[kk][tx * 8];
            *(float4*)&b[4] = *(const float4*)&Bs[kk][tx * 8 + 4];
            #pragma unroll
            for (int i = 0; i < 8; ++i)
                #pragma unroll
                for (int j = 0; j < 8; ++j)
                    acc[i][j] = fmaf(a[i], b[j], acc[i][j]);
        }
        __syncthreads();
    }
    float bv[8];
    *(float4*)&bv[0] = *(const float4*)&bias[bn + tx * 8];
    *(float4*)&bv[4] = *(const float4*)&bias[bn + tx * 8 + 4];
    #pragma unroll
    for (int i = 0; i < 8; ++i) {
        int m = bm + ty * 8 + i;
        if (m < M) {
            float o[8];
            #pragma unroll
            for (int j = 0; j < 8; ++j) o[j] = fmaxf(acc[i][j] + bv[j], 0.f);
            if constexpr (BF16_OUT) {
                unsigned short* C = (unsigned short*)Cv;
                ushort8 u;
                #pragma unroll
                for (int j = 0; j < 8; ++j) u[j] = f2bf(o[j]);
                *(ushort8*)&C[(size_t)m * Nc + bn + tx * 8] = u;
            } else {
                float* C = (float*)Cv;
                float* cp = &C[(size_t)m * Nc + bn + tx * 8];
                *(float4*)cp = *(float4*)&o[0];
                *(float4*)(cp + 4) = *(float4*)&o[4];
            }
        }
    }
}

// ---------------- pool + head: one block per graph ----------------

__device__ __forceinline__ int lower_bound_i(const int* __restrict__ a, int n, int v) {
    int lo = 0, hi = n;
    while (lo < hi) {
        int mid = (lo + hi) >> 1;
        if (a[mid] < v) lo = mid + 1; else hi = mid;
    }
    return lo;
}

__global__ __launch_bounds__(256) void pool_head(const float* __restrict__ h,
                                                 const int* __restrict__ batch,
                                                 const float* __restrict__ num_atoms,
                                                 const float* __restrict__ W3, const float* __restrict__ b3,
                                                 const float* __restrict__ W4, const float* __restrict__ b4,
                                                 float* __restrict__ out, int n) {
    int g = blockIdx.x;
    int tid = threadIdx.x;
    __shared__ int s_lo, s_hi;
    if (tid == 0) {
        s_lo = lower_bound_i(batch, n, g);
        s_hi = lower_bound_i(batch, n, g + 1);
    }
    __syncthreads();
    int lo = s_lo, hi = s_hi;
    float sum = 0.f;
    for (int i = lo; i < hi; ++i) sum += h[(size_t)i * HDIM + tid];
    float cnt = (float)(hi - lo);
    float pooled = sum / fmaxf(cnt, 1.0f);

    __shared__ float zin[HDIM + 1];
    __shared__ float z[32];
    zin[tid] = pooled;
    if (tid == 0) zin[HDIM] = num_atoms[g];
    __syncthreads();
    if (tid < 32) {
        float a = b3[tid];
        for (int k = 0; k < HDIM + 1; ++k) a = fmaf(zin[k], W3[k * 32 + tid], a);
        z[tid] = fmaxf(a, 0.f);
    }
    __syncthreads();
    if (tid < 4) {
        float a = b4[tid];
        #pragma unroll
        for (int k = 0; k < 32; ++k) a = fmaf(z[k], W4[k * 4 + tid], a);
        out[g * 4 + tid] = a;
    }
}

// ---------------- launch ----------------

extern "C" void kernel_launch(void* const* d_in, const int* in_sizes, int n_in,
                              void* d_out, int out_size, void* d_ws, size_t ws_size,
                              hipStream_t stream) {
    const float* x         = (const float*)d_in[0];
    const int*   edge_idx  = (const int*)d_in[1];
    const int*   batch     = (const int*)d_in[2];
    const float* num_atoms = (const float*)d_in[3];
    const float* W1 = (const float*)d_in[4];
    const float* b1 = (const float*)d_in[5];
    const float* W2 = (const float*)d_in[6];
    const float* b2 = (const float*)d_in[7];
    const float* W3 = (const float*)d_in[8];
    const float* b3 = (const float*)d_in[9];
    const float* W4 = (const float*)d_in[10];
    const float* b4 = (const float*)d_in[11];
    float* out = (float*)d_out;

    const int n = NN, e = EE;
    const int* e_src = edge_idx;
    const int* e_dst = edge_idx + e;

    // workspace carve-out (256B aligned). Aliasing (lifetimes don't overlap):
    //   R1 [N*256 f32]: a0 = R1[0:N*128] (agg128 out, dead after GEMM1);
    //                   x_bf = R1[N*128 : N*128 + N*128/2 f32-slots] (dead after agg128... NO —
    //                   x_bf is read BY agg128 which writes a0; keep them disjoint inside R1);
    //                   a1 = full R1 (written by agg256 after both are dead)
    //   R2 [N*256 f32]: h1b = R2[0:N*128] as bf16 (GEMM1 out, dead after agg256);
    //                   h2 = full R2 (GEMM2 out, written after agg256 completes... GEMM2 writes
    //                   after reading a1; h1b dead by then)
    char* ws = (char*)d_ws;
    size_t off = 0;
    auto carve = [&](size_t bytes) -> void* {
        void* p = ws + off;
        off = (off + bytes + 255) & ~(size_t)255;
        return p;
    };
    int*   deg_i    = (int*)carve((size_t)n * 4);
    int*   row_off  = (int*)carve((size_t)(n + 1) * 4);
    int*   fill     = (int*)carve((size_t)n * 4);
    int*   blk_sums = (int*)carve((size_t)256 * 4);
    float* dinv     = (float*)carve((size_t)n * 4);
    int2*  csr      = (int2*)carve((size_t)e * 8);
    float* R1       = (float*)carve((size_t)n * HDIM * 4);
    float* R2       = (float*)carve((size_t)n * HDIM * 4);
    float*          a0   = R1;                                   // [N,128] fp32
    unsigned short* x_bf = (unsigned short*)(R1 + (size_t)n * 128);  // [N,128] bf16
    float*          a1   = R1;                                   // [N,256] fp32
    unsigned short* h1b  = (unsigned short*)R2;                  // [N,256] bf16
    float*          h2   = R2;                                   // [N,256] fp32
    (void)ws_size; (void)n_in; (void)in_sizes; (void)out_size;

    hipMemsetAsync(deg_i, 0, (size_t)n * 4, stream);
    hist_kernel<<<1024, 256, 0, stream>>>(e_dst, deg_i, e);
    scan_part<<<SCAN_NB, 256, 0, stream>>>(deg_i, row_off, blk_sums, dinv, n);
    scan_sums<<<1, 256, 0, stream>>>(blk_sums, SCAN_NB);
    scan_add<<<SCAN_NB, 256, 0, stream>>>(row_off, blk_sums, fill, n, e);
    scatter_kernel<<<1024, 256, 0, stream>>>(e_src, e_dst, row_off, fill, dinv, csr, e);

    cast_f32_bf16<<<1024, 256, 0, stream>>>(x, x_bf, n * FDIM);

    dim3 gemm_grid((n + 127) / 128, HDIM / 128);
    // L1: a0 = agg(x_bf) [N,128] fp32; h1b = relu(a0 @ W1 + b1) -> bf16
    gcn_agg128_bf16<<<(n + 3) / 4, 256, 0, stream>>>(x_bf, row_off, csr, dinv, a0, n);
    gemm_bias_relu<true><<<gemm_grid, 256, 0, stream>>>(a0, W1, b1, h1b, n, FDIM, HDIM);
    // L2: a1 = agg(h1b) [N,256] fp32; h2 = relu(a1 @ W2 + b2) fp32
    gcn_agg256_bf16<<<(n + 3) / 4, 256, 0, stream>>>(h1b, row_off, csr, dinv, a1, n);
    gemm_bias_relu<false><<<gemm_grid, 256, 0, stream>>>(a1, W2, b2, h2, n, HDIM, HDIM);
    // pool + head
    pool_head<<<GG, 256, 0, stream>>>(h2, batch, num_atoms, W3, b3, W4, b4, out, n);
}

// Round 7
// 372.508 us; speedup vs baseline: 2.0875x; 1.2398x over previous
//
#include <hip/hip_runtime.h>
#include <hip/hip_bf16.h>

// GNN: 2-layer GCN (N=50000, E=800000, F=128, H=256) + mean-pool (G=512) + MLP head (257->32->4)
// Key identity: segment_sum((xW)[src]*norm) == (segment_sum(x[src]*norm)) @ W  (GCN agg is linear)
//   prep:  deg histogram -> hierarchical scan (dinv fused) -> packed CSR scatter (int2{src,w})
//   L1: cast x->bf16; agg128 -> a0 (bf16); h1 = relu(a0 @ W1 + b1) -> bf16   [MFMA]
//   L2: agg256(h1) -> a1 (bf16); h2 = relu(a1 @ W2 + b2) -> fp32             [MFMA]
//   head: per-graph block: mean-pool + 257->32->4 MLP
// R5: agg is L2-miss-path bound -> R6 bf16 payloads (462us). R7: fp32 VALU GEMM (110us, 60TF,
// 8M LDS conflicts) -> bf16 MFMA GEMM (v_mfma_f32_16x16x32_bf16), fp32 accumulate.

#define NN 50000
#define EE 800000
#define FDIM 128
#define HDIM 256
#define GG 512
#define SCAN_NB ((NN + 255) / 256)

typedef __attribute__((ext_vector_type(8))) short short8;     // 8 bf16 = 4 VGPRs (MFMA A/B frag)
typedef __attribute__((ext_vector_type(4))) float floatx4;    // MFMA C/D frag

__device__ __forceinline__ unsigned short f2bf(float f) {   // RNE
    unsigned u = __float_as_uint(f);
    return (unsigned short)((u + 0x7FFF + ((u >> 16) & 1)) >> 16);
}
__device__ __forceinline__ float bflo(unsigned v) { return __uint_as_float(v << 16); }
__device__ __forceinline__ float bfhi(unsigned v) { return __uint_as_float(v & 0xFFFF0000u); }

// ---------------- prep kernels ----------------

__global__ void hist_kernel(const int* __restrict__ dst, int* __restrict__ deg, int e) {
    int i = blockIdx.x * blockDim.x + threadIdx.x;
    int stride = gridDim.x * blockDim.x;
    for (; i < e; i += stride) atomicAdd(&deg[dst[i]], 1);
}

__global__ __launch_bounds__(256) void scan_part(const int* __restrict__ deg,
                                                 int* __restrict__ row_off,
                                                 int* __restrict__ blk_sums,
                                                 float* __restrict__ dinv, int n) {
    __shared__ int s[256];
    int tid = threadIdx.x;
    int i = blockIdx.x * 256 + tid;
    int v = (i < n) ? deg[i] : 0;
    if (i < n) dinv[i] = rsqrtf((float)v + 1.0f);
    s[tid] = v;
    __syncthreads();
    #pragma unroll
    for (int off = 1; off < 256; off <<= 1) {
        int t = (tid >= off) ? s[tid - off] : 0;
        __syncthreads();
        s[tid] += t;
        __syncthreads();
    }
    if (i < n) row_off[i] = s[tid] - v;
    if (tid == 255) blk_sums[blockIdx.x] = s[255];
}

__global__ __launch_bounds__(256) void scan_sums(int* __restrict__ blk_sums, int nb) {
    __shared__ int s[256];
    int tid = threadIdx.x;
    int v = (tid < nb) ? blk_sums[tid] : 0;
    s[tid] = v;
    __syncthreads();
    #pragma unroll
    for (int off = 1; off < 256; off <<= 1) {
        int t = (tid >= off) ? s[tid - off] : 0;
        __syncthreads();
        s[tid] += t;
        __syncthreads();
    }
    if (tid < nb) blk_sums[tid] = s[tid] - v;
}

__global__ __launch_bounds__(256) void scan_add(int* __restrict__ row_off,
                                                const int* __restrict__ blk_sums,
                                                int* __restrict__ fill, int n, int e) {
    int i = blockIdx.x * 256 + threadIdx.x;
    if (i < n) {
        row_off[i] += blk_sums[blockIdx.x];
        fill[i] = 0;
    }
    if (i == 0) row_off[n] = e;
}

__global__ void scatter_kernel(const int* __restrict__ src, const int* __restrict__ dst,
                               const int* __restrict__ row_off, int* __restrict__ fill,
                               const float* __restrict__ dinv,
                               int2* __restrict__ csr, int e) {
    int i = blockIdx.x * blockDim.x + threadIdx.x;
    int stride = gridDim.x * blockDim.x;
    for (; i < e; i += stride) {
        int s = src[i], d = dst[i];
        int pos = row_off[d] + atomicAdd(&fill[d], 1);
        csr[pos] = make_int2(s, __float_as_int(dinv[s] * dinv[d]));
    }
}

// fp32 -> bf16 cast, vectorized (count multiple of 4)
__global__ void cast_f32_bf16(const float* __restrict__ in, unsigned short* __restrict__ out,
                              int count) {
    int i = (blockIdx.x * blockDim.x + threadIdx.x) * 4;
    int stride = gridDim.x * blockDim.x * 4;
    for (; i < count; i += stride) {
        float4 v = *(const float4*)&in[i];
        ushort4 o;
        o.x = f2bf(v.x); o.y = f2bf(v.y); o.z = f2bf(v.z); o.w = f2bf(v.w);
        *(ushort4*)&out[i] = o;
    }
}

// Wt[n][k] = bf16(W[k][n]) ; tiny, launched once per weight
__global__ void transpose_cast_bf16(const float* __restrict__ W, unsigned short* __restrict__ Wt,
                                    int K, int Nc) {
    int idx = blockIdx.x * blockDim.x + threadIdx.x;
    if (idx < K * Nc) {
        int nn = idx / K, k = idx - nn * K;
        Wt[idx] = f2bf(W[(size_t)k * Nc + nn]);
    }
}

// ---------------- GCN aggregation (bf16 payload, fp32 accumulate, bf16 out) ----------------
// out[d] = sum_e in[src_e]*w_e + in[d]*dinv[d]^2
// one wave per node; wave-uniform bounds, int4 CSR loads, 4-deep gather pipeline

__global__ __launch_bounds__(256) void gcn_agg256_bf16(const unsigned short* __restrict__ in,
                                                       const int* __restrict__ row_off,
                                                       const int2* __restrict__ csr,
                                                       const float* __restrict__ dinv,
                                                       unsigned short* __restrict__ out, int n) {
    int wave = threadIdx.x >> 6;
    int lane = threadIdx.x & 63;
    int node = blockIdx.x * 4 + wave;
    if (node >= n) return;
    float di = dinv[node];
    float w0 = di * di;
    uint2 hu = *(const uint2*)&in[(size_t)node * 256 + lane * 4];
    float4 acc;
    acc.x = bflo(hu.x) * w0; acc.y = bfhi(hu.x) * w0;
    acc.z = bflo(hu.y) * w0; acc.w = bfhi(hu.y) * w0;
    int beg = __builtin_amdgcn_readfirstlane(row_off[node]);
    int end = __builtin_amdgcn_readfirstlane(row_off[node + 1]);
    int e = beg;
    if ((e & 1) && e < end) {
        int2 p = csr[e];
        uint2 u = *(const uint2*)&in[(size_t)p.x * 256 + lane * 4];
        float w = __int_as_float(p.y);
        acc.x = fmaf(bflo(u.x), w, acc.x); acc.y = fmaf(bfhi(u.x), w, acc.y);
        acc.z = fmaf(bflo(u.y), w, acc.z); acc.w = fmaf(bfhi(u.y), w, acc.w);
        ++e;
    }
    int nmain = (end - e) >> 2;
    if (nmain > 0) {
        const int4* cp = (const int4*)&csr[e];
        int4 q0 = cp[0], q1 = cp[1];
        for (int it = 1; it < nmain; ++it) {
            int4 r0 = cp[2 * it], r1 = cp[2 * it + 1];
            uint2 u0 = *(const uint2*)&in[(size_t)q0.x * 256 + lane * 4];
            uint2 u1 = *(const uint2*)&in[(size_t)q0.z * 256 + lane * 4];
            uint2 u2 = *(const uint2*)&in[(size_t)q1.x * 256 + lane * 4];
            uint2 u3 = *(const uint2*)&in[(size_t)q1.z * 256 + lane * 4];
            float wa = __int_as_float(q0.y), wb = __int_as_float(q0.w);
            float wc = __int_as_float(q1.y), wd = __int_as_float(q1.w);
            acc.x = fmaf(bflo(u0.x), wa, acc.x); acc.y = fmaf(bfhi(u0.x), wa, acc.y);
            acc.z = fmaf(bflo(u0.y), wa, acc.z); acc.w = fmaf(bfhi(u0.y), wa, acc.w);
            acc.x = fmaf(bflo(u1.x), wb, acc.x); acc.y = fmaf(bfhi(u1.x), wb, acc.y);
            acc.z = fmaf(bflo(u1.y), wb, acc.z); acc.w = fmaf(bfhi(u1.y), wb, acc.w);
            acc.x = fmaf(bflo(u2.x), wc, acc.x); acc.y = fmaf(bfhi(u2.x), wc, acc.y);
            acc.z = fmaf(bflo(u2.y), wc, acc.z); acc.w = fmaf(bfhi(u2.y), wc, acc.w);
            acc.x = fmaf(bflo(u3.x), wd, acc.x); acc.y = fmaf(bfhi(u3.x), wd, acc.y);
            acc.z = fmaf(bflo(u3.y), wd, acc.z); acc.w = fmaf(bfhi(u3.y), wd, acc.w);
            q0 = r0; q1 = r1;
        }
        {
            uint2 u0 = *(const uint2*)&in[(size_t)q0.x * 256 + lane * 4];
            uint2 u1 = *(const uint2*)&in[(size_t)q0.z * 256 + lane * 4];
            uint2 u2 = *(const uint2*)&in[(size_t)q1.x * 256 + lane * 4];
            uint2 u3 = *(const uint2*)&in[(size_t)q1.z * 256 + lane * 4];
            float wa = __int_as_float(q0.y), wb = __int_as_float(q0.w);
            float wc = __int_as_float(q1.y), wd = __int_as_float(q1.w);
            acc.x = fmaf(bflo(u0.x), wa, acc.x); acc.y = fmaf(bfhi(u0.x), wa, acc.y);
            acc.z = fmaf(bflo(u0.y), wa, acc.z); acc.w = fmaf(bfhi(u0.y), wa, acc.w);
            acc.x = fmaf(bflo(u1.x), wb, acc.x); acc.y = fmaf(bfhi(u1.x), wb, acc.y);
            acc.z = fmaf(bflo(u1.y), wb, acc.z); acc.w = fmaf(bfhi(u1.y), wb, acc.w);
            acc.x = fmaf(bflo(u2.x), wc, acc.x); acc.y = fmaf(bfhi(u2.x), wc, acc.y);
            acc.z = fmaf(bflo(u2.y), wc, acc.z); acc.w = fmaf(bfhi(u2.y), wc, acc.w);
            acc.x = fmaf(bflo(u3.x), wd, acc.x); acc.y = fmaf(bfhi(u3.x), wd, acc.y);
            acc.z = fmaf(bflo(u3.y), wd, acc.z); acc.w = fmaf(bfhi(u3.y), wd, acc.w);
        }
        e += nmain * 4;
    }
    for (; e < end; ++e) {
        int2 p = csr[e];
        uint2 u = *(const uint2*)&in[(size_t)p.x * 256 + lane * 4];
        float w = __int_as_float(p.y);
        acc.x = fmaf(bflo(u.x), w, acc.x); acc.y = fmaf(bfhi(u.x), w, acc.y);
        acc.z = fmaf(bflo(u.y), w, acc.z); acc.w = fmaf(bfhi(u.y), w, acc.w);
    }
    ushort4 o;
    o.x = f2bf(acc.x); o.y = f2bf(acc.y); o.z = f2bf(acc.z); o.w = f2bf(acc.w);
    *(ushort4*)&out[(size_t)node * 256 + lane * 4] = o;
}

__global__ __launch_bounds__(256) void gcn_agg128_bf16(const unsigned short* __restrict__ in,
                                                       const int* __restrict__ row_off,
                                                       const int2* __restrict__ csr,
                                                       const float* __restrict__ dinv,
                                                       unsigned short* __restrict__ out, int n) {
    int wave = threadIdx.x >> 6;
    int lane = threadIdx.x & 63;
    int node = blockIdx.x * 4 + wave;
    if (node >= n) return;
    float di = dinv[node];
    float w0 = di * di;
    unsigned hu = *(const unsigned*)&in[(size_t)node * 128 + lane * 2];
    float2 acc = {bflo(hu) * w0, bfhi(hu) * w0};
    int beg = __builtin_amdgcn_readfirstlane(row_off[node]);
    int end = __builtin_amdgcn_readfirstlane(row_off[node + 1]);
    int e = beg;
    if ((e & 1) && e < end) {
        int2 p = csr[e];
        unsigned u = *(const unsigned*)&in[(size_t)p.x * 128 + lane * 2];
        float w = __int_as_float(p.y);
        acc.x = fmaf(bflo(u), w, acc.x);
        acc.y = fmaf(bfhi(u), w, acc.y);
        ++e;
    }
    int nmain = (end - e) >> 2;
    if (nmain > 0) {
        const int4* cp = (const int4*)&csr[e];
        int4 q0 = cp[0], q1 = cp[1];
        for (int it = 1; it < nmain; ++it) {
            int4 r0 = cp[2 * it], r1 = cp[2 * it + 1];
            unsigned u0 = *(const unsigned*)&in[(size_t)q0.x * 128 + lane * 2];
            unsigned u1 = *(const unsigned*)&in[(size_t)q0.z * 128 + lane * 2];
            unsigned u2 = *(const unsigned*)&in[(size_t)q1.x * 128 + lane * 2];
            unsigned u3 = *(const unsigned*)&in[(size_t)q1.z * 128 + lane * 2];
            float wa = __int_as_float(q0.y), wb = __int_as_float(q0.w);
            float wc = __int_as_float(q1.y), wd = __int_as_float(q1.w);
            acc.x = fmaf(bflo(u0), wa, acc.x); acc.y = fmaf(bfhi(u0), wa, acc.y);
            acc.x = fmaf(bflo(u1), wb, acc.x); acc.y = fmaf(bfhi(u1), wb, acc.y);
            acc.x = fmaf(bflo(u2), wc, acc.x); acc.y = fmaf(bfhi(u2), wc, acc.y);
            acc.x = fmaf(bflo(u3), wd, acc.x); acc.y = fmaf(bfhi(u3), wd, acc.y);
            q0 = r0; q1 = r1;
        }
        {
            unsigned u0 = *(const unsigned*)&in[(size_t)q0.x * 128 + lane * 2];
            unsigned u1 = *(const unsigned*)&in[(size_t)q0.z * 128 + lane * 2];
            unsigned u2 = *(const unsigned*)&in[(size_t)q1.x * 128 + lane * 2];
            unsigned u3 = *(const unsigned*)&in[(size_t)q1.z * 128 + lane * 2];
            float wa = __int_as_float(q0.y), wb = __int_as_float(q0.w);
            float wc = __int_as_float(q1.y), wd = __int_as_float(q1.w);
            acc.x = fmaf(bflo(u0), wa, acc.x); acc.y = fmaf(bfhi(u0), wa, acc.y);
            acc.x = fmaf(bflo(u1), wb, acc.x); acc.y = fmaf(bfhi(u1), wb, acc.y);
            acc.x = fmaf(bflo(u2), wc, acc.x); acc.y = fmaf(bfhi(u2), wc, acc.y);
            acc.x = fmaf(bflo(u3), wd, acc.x); acc.y = fmaf(bfhi(u3), wd, acc.y);
        }
        e += nmain * 4;
    }
    for (; e < end; ++e) {
        int2 p = csr[e];
        unsigned u = *(const unsigned*)&in[(size_t)p.x * 128 + lane * 2];
        float w = __int_as_float(p.y);
        acc.x = fmaf(bflo(u), w, acc.x);
        acc.y = fmaf(bfhi(u), w, acc.y);
    }
    unsigned o = (unsigned)f2bf(acc.x) | ((unsigned)f2bf(acc.y) << 16);
    *(unsigned*)&out[(size_t)node * 128 + lane * 2] = o;
}

// ---------------- bf16 MFMA GEMM + bias + ReLU ----------------
// C[M,Nc] = relu(A[M,K] @ B[K,Nc] + bias), A bf16 row-major, Bt bf16 [Nc][K] (pre-transposed).
// 128x128 block tile, 4 waves (2x2), each wave 64x64 via 4x4 v_mfma_f32_16x16x32_bf16.
// Verified layouts (learn_hip m89/m91/m120): A-frag A[m=lane&15][k=quad*8+j];
// B-frag B[k=quad*8+j][n=lane&15]; C/D col=lane&15, row=quad*4+reg.
// LDS rows padded to 40 bf16 (80B, non-pow2) -> <=2-way conflicts on b128 frag reads.

template<bool BF16_OUT>
__global__ __launch_bounds__(256) void gemm_mfma_bias_relu(
        const unsigned short* __restrict__ A,    // [M][K] bf16
        const unsigned short* __restrict__ Bt,   // [Nc][K] bf16
        const float* __restrict__ bias,          // [Nc] fp32
        void* __restrict__ Cv, int M, int K, int Nc) {
    constexpr int LDT = 40;                      // padded LDS row (ushorts)
    __shared__ unsigned short As[128 * LDT];     // A rows (m-major, k contiguous)
    __shared__ unsigned short Bs[128 * LDT];     // B cols (n-major, k contiguous)
    int tid = threadIdx.x;
    int lane = tid & 63, wave = tid >> 6;
    int wm = (wave >> 1) * 64, wn = (wave & 1) * 64;
    int bm = blockIdx.x * 128, bn = blockIdx.y * 128;
    int l15 = lane & 15, quad = lane >> 4;

    floatx4 zero = {0.f, 0.f, 0.f, 0.f};
    floatx4 acc[4][4];
    #pragma unroll
    for (int s = 0; s < 4; ++s)
        #pragma unroll
        for (int t = 0; t < 4; ++t) acc[s][t] = zero;

    for (int k0 = 0; k0 < K; k0 += 32) {
        // stage: 512 16B-chunks each for A and B; thread handles chunks tid and tid+256
        #pragma unroll
        for (int c = tid; c < 512; c += 256) {
            int row = c >> 2, q = c & 3;
            int4 va = {0, 0, 0, 0};
            int gr = bm + row;
            if (gr < M) va = *(const int4*)&A[(size_t)gr * K + k0 + q * 8];
            *(int4*)&As[row * LDT + q * 8] = va;
            int4 vb = *(const int4*)&Bt[(size_t)(bn + row) * K + k0 + q * 8];
            *(int4*)&Bs[row * LDT + q * 8] = vb;
        }
        __syncthreads();
        short8 af[4], bf[4];
        #pragma unroll
        for (int s = 0; s < 4; ++s)
            af[s] = *(const short8*)&As[(wm + s * 16 + l15) * LDT + quad * 8];
        #pragma unroll
        for (int t = 0; t < 4; ++t)
            bf[t] = *(const short8*)&Bs[(wn + t * 16 + l15) * LDT + quad * 8];
        #pragma unroll
        for (int s = 0; s < 4; ++s)
            #pragma unroll
            for (int t = 0; t < 4; ++t)
                acc[s][t] = __builtin_amdgcn_mfma_f32_16x16x32_bf16(af[s], bf[t], acc[s][t], 0, 0, 0);
        __syncthreads();
    }
    // epilogue: D[row=quad*4+r][col=lane&15] per 16x16 subtile
    #pragma unroll
    for (int s = 0; s < 4; ++s) {
        int row0 = bm + wm + s * 16 + quad * 4;
        #pragma unroll
        for (int t = 0; t < 4; ++t) {
            int col = bn + wn + t * 16 + l15;
            float bb = bias[col];
            #pragma unroll
            for (int r = 0; r < 4; ++r) {
                int row = row0 + r;
                if (row < M) {
                    float o = fmaxf(acc[s][t][r] + bb, 0.f);
                    if constexpr (BF16_OUT)
                        ((unsigned short*)Cv)[(size_t)row * Nc + col] = f2bf(o);
                    else
                        ((float*)Cv)[(size_t)row * Nc + col] = o;
                }
            }
        }
    }
}

// ---------------- pool + head: one block per graph ----------------

__device__ __forceinline__ int lower_bound_i(const int* __restrict__ a, int n, int v) {
    int lo = 0, hi = n;
    while (lo < hi) {
        int mid = (lo + hi) >> 1;
        if (a[mid] < v) lo = mid + 1; else hi = mid;
    }
    return lo;
}

__global__ __launch_bounds__(256) void pool_head(const float* __restrict__ h,
                                                 const int* __restrict__ batch,
                                                 const float* __restrict__ num_atoms,
                                                 const float* __restrict__ W3, const float* __restrict__ b3,
                                                 const float* __restrict__ W4, const float* __restrict__ b4,
                                                 float* __restrict__ out, int n) {
    int g = blockIdx.x;
    int tid = threadIdx.x;
    __shared__ int s_lo, s_hi;
    if (tid == 0) {
        s_lo = lower_bound_i(batch, n, g);
        s_hi = lower_bound_i(batch, n, g + 1);
    }
    __syncthreads();
    int lo = s_lo, hi = s_hi;
    float sum = 0.f;
    for (int i = lo; i < hi; ++i) sum += h[(size_t)i * HDIM + tid];
    float cnt = (float)(hi - lo);
    float pooled = sum / fmaxf(cnt, 1.0f);

    __shared__ float zin[HDIM + 1];
    __shared__ float z[32];
    zin[tid] = pooled;
    if (tid == 0) zin[HDIM] = num_atoms[g];
    __syncthreads();
    if (tid < 32) {
        float a = b3[tid];
        for (int k = 0; k < HDIM + 1; ++k) a = fmaf(zin[k], W3[k * 32 + tid], a);
        z[tid] = fmaxf(a, 0.f);
    }
    __syncthreads();
    if (tid < 4) {
        float a = b4[tid];
        #pragma unroll
        for (int k = 0; k < 32; ++k) a = fmaf(z[k], W4[k * 4 + tid], a);
        out[g * 4 + tid] = a;
    }
}

// ---------------- launch ----------------

extern "C" void kernel_launch(void* const* d_in, const int* in_sizes, int n_in,
                              void* d_out, int out_size, void* d_ws, size_t ws_size,
                              hipStream_t stream) {
    const float* x         = (const float*)d_in[0];
    const int*   edge_idx  = (const int*)d_in[1];
    const int*   batch     = (const int*)d_in[2];
    const float* num_atoms = (const float*)d_in[3];
    const float* W1 = (const float*)d_in[4];
    const float* b1 = (const float*)d_in[5];
    const float* W2 = (const float*)d_in[6];
    const float* b2 = (const float*)d_in[7];
    const float* W3 = (const float*)d_in[8];
    const float* b3 = (const float*)d_in[9];
    const float* W4 = (const float*)d_in[10];
    const float* b4 = (const float*)d_in[11];
    float* out = (float*)d_out;

    const int n = NN, e = EE;
    const int* e_src = edge_idx;
    const int* e_dst = edge_idx + e;

    // workspace (256B aligned). Lifetime aliasing:
    //   P (25.6MB): {x_bf [N,128]bf16 ; a0b [N,128]bf16} live together through gemm1,
    //               then whole P reused as a1b [N,256]bf16 (agg256 out).
    //   Q (25.6MB): h1b [N,256]bf16 (gemm1 out, dead after agg256).
    //   R (51.2MB): h2 [N,256]fp32 (gemm2 out -> pool).
    char* ws = (char*)d_ws;
    size_t off = 0;
    auto carve = [&](size_t bytes) -> void* {
        void* p = ws + off;
        off = (off + bytes + 255) & ~(size_t)255;
        return p;
    };
    int*   deg_i    = (int*)carve((size_t)n * 4);
    int*   row_off  = (int*)carve((size_t)(n + 1) * 4);
    int*   fill     = (int*)carve((size_t)n * 4);
    int*   blk_sums = (int*)carve((size_t)256 * 4);
    float* dinv     = (float*)carve((size_t)n * 4);
    unsigned short* W1t = (unsigned short*)carve((size_t)FDIM * HDIM * 2);
    unsigned short* W2t = (unsigned short*)carve((size_t)HDIM * HDIM * 2);
    int2*  csr      = (int2*)carve((size_t)e * 8);
    unsigned short* P = (unsigned short*)carve((size_t)n * HDIM * 2);
    unsigned short* Q = (unsigned short*)carve((size_t)n * HDIM * 2);
    float*          R = (float*)carve((size_t)n * HDIM * 4);
    unsigned short* x_bf = P;                       // [N,128] bf16
    unsigned short* a0b  = P + (size_t)n * FDIM;    // [N,128] bf16
    unsigned short* a1b  = P;                       // [N,256] bf16 (x_bf/a0b dead)
    unsigned short* h1b  = Q;                       // [N,256] bf16
    float*          h2   = R;                       // [N,256] fp32
    (void)ws_size; (void)n_in; (void)in_sizes; (void)out_size;

    hipMemsetAsync(deg_i, 0, (size_t)n * 4, stream);
    hist_kernel<<<1024, 256, 0, stream>>>(e_dst, deg_i, e);
    scan_part<<<SCAN_NB, 256, 0, stream>>>(deg_i, row_off, blk_sums, dinv, n);
    scan_sums<<<1, 256, 0, stream>>>(blk_sums, SCAN_NB);
    scan_add<<<SCAN_NB, 256, 0, stream>>>(row_off, blk_sums, fill, n, e);
    scatter_kernel<<<1024, 256, 0, stream>>>(e_src, e_dst, row_off, fill, dinv, csr, e);

    cast_f32_bf16<<<1024, 256, 0, stream>>>(x, x_bf, n * FDIM);
    transpose_cast_bf16<<<(FDIM * HDIM + 255) / 256, 256, 0, stream>>>(W1, W1t, FDIM, HDIM);
    transpose_cast_bf16<<<(HDIM * HDIM + 255) / 256, 256, 0, stream>>>(W2, W2t, HDIM, HDIM);

    dim3 gemm_grid((n + 127) / 128, HDIM / 128);
    // L1: a0 = agg(x_bf) bf16; h1b = relu(a0 @ W1 + b1) bf16
    gcn_agg128_bf16<<<(n + 3) / 4, 256, 0, stream>>>(x_bf, row_off, csr, dinv, a0b, n);
    gemm_mfma_bias_relu<true><<<gemm_grid, 256, 0, stream>>>(a0b, W1t, b1, h1b, n, FDIM, HDIM);
    // L2: a1 = agg(h1b) bf16; h2 = relu(a1 @ W2 + b2) fp32
    gcn_agg256_bf16<<<(n + 3) / 4, 256, 0, stream>>>(h1b, row_off, csr, dinv, a1b, n);
    gemm_mfma_bias_relu<false><<<gemm_grid, 256, 0, stream>>>(a1b, W2t, b2, h2, n, HDIM, HDIM);
    // pool + head
    pool_head<<<GG, 256, 0, stream>>>(h2, batch, num_atoms, W3, b3, W4, b4, out, n);
}